// Round 15
// baseline (347.015 us; speedup 1.0000x reference)
//
#include <hip/hip_runtime.h>
#include <stdint.h>

constexpr int NROW = 50000;
constexpr int NCOL = 50000;
constexpr int DH   = 128;
constexpr int NTAB = 200000;   // [out_rc(NROW) | in_rc(NCOL) | out_cr(NCOL) | in_cr(NROW)]
constexpr int HB   = 12500;    // bins per section (quarter table), 50 KB LDS
constexpr int HBLK = 64;       // blocks per section
constexpr int DGRID = 1250;    // dense blocks per relation
constexpr int GGRID = 2048;    // gather blocks per relation
constexpr int CH    = 500;     // scan chunk size (100 chunks per table)

typedef __attribute__((ext_vector_type(8))) short short8;
typedef __attribute__((ext_vector_type(4))) float f32x4;
typedef __attribute__((ext_vector_type(2))) float f32x2;

__device__ __forceinline__ float bf_hi(unsigned u) { return __uint_as_float(u & 0xffff0000u); }
__device__ __forceinline__ unsigned short f2bf(float f) {   // RNE
    unsigned u = __float_as_uint(f);
    return (unsigned short)((u + 0x7fffu + ((u >> 16) & 1u)) >> 16);
}

// ---- fp8 OCP e4m3fn encode (RNE, clamp 448, subnormal-aware) ----
__device__ __forceinline__ unsigned char f2fp8(float f) {
    unsigned b = __float_as_uint(f);
    unsigned s = (b >> 24) & 0x80u;
    unsigned mag = b & 0x7fffffffu;
    if (mag >= 0x43e00000u) return (unsigned char)(s | 0x7eu);   // clamp to ±448
    unsigned r = mag + 0x7ffffu + ((mag >> 20) & 1u);
    int e = (int)(r >> 23) - 120;
    if (e < 1) {                                                  // subnormal: m * 2^-9
        float af = __uint_as_float(mag);
        unsigned m = (unsigned)(af * 512.f + 0.5f);
        if (m > 8u) m = 8u;
        return (unsigned char)(s | m);
    }
    return (unsigned char)(s | (unsigned)(e << 3) | ((r >> 20) & 7u));
}

// ---- fp8 decode helpers (HW cvt if available) ----
#if defined(__has_builtin) && __has_builtin(__builtin_amdgcn_cvt_pk_f32_fp8)
__device__ __forceinline__ f32x2 fp8x2f(unsigned v) {
    return __builtin_amdgcn_cvt_pk_f32_fp8((int)v, false);
}
__device__ __forceinline__ f32x4 fp8x4f(unsigned v) {
    f32x2 lo = __builtin_amdgcn_cvt_pk_f32_fp8((int)v, false);
    f32x2 hi = __builtin_amdgcn_cvt_pk_f32_fp8((int)v, true);
    f32x4 r; r.x = lo.x; r.y = lo.y; r.z = hi.x; r.w = hi.y; return r;
}
#else
__device__ __forceinline__ float fp8_1(unsigned u) {
    unsigned s = (u & 0x80u) << 24, em = u & 0x7fu;
    if (em >= 8u) return __uint_as_float(s | ((em + 960u) << 20));
    float v = (float)em * 0.001953125f;
    return (u & 0x80u) ? -v : v;
}
__device__ __forceinline__ f32x2 fp8x2f(unsigned v) {
    f32x2 r; r.x = fp8_1(v & 0xffu); r.y = fp8_1((v >> 8) & 0xffu); return r;
}
__device__ __forceinline__ f32x4 fp8x4f(unsigned v) {
    f32x4 r; r.x = fp8_1(v & 0xffu); r.y = fp8_1((v >> 8) & 0xffu);
    r.z = fp8_1((v >> 16) & 0xffu); r.w = fp8_1((v >> 24) & 0xffu); return r;
}
#endif

// ---- degree histograms via LDS privatization; u16 partials (max/block 18750) ----
__global__ __launch_bounds__(512) void hist_lds(
        const int* __restrict__ s_rc, const int* __restrict__ d_rc,
        const int* __restrict__ s_cr, const int* __restrict__ d_cr,
        unsigned short* __restrict__ partial, int E) {
    __shared__ int h[HB];
    const int sec = blockIdx.x >> 6;           // 0..15
    const int blk = blockIdx.x & (HBLK - 1);
    const int tab = sec >> 2;                  // 0..3 -> array
    const int lo  = (sec & 3) * HB;
    const int* __restrict__ arr = (tab == 0) ? s_rc : (tab == 1) ? d_rc
                                 : (tab == 2) ? s_cr : d_cr;
    for (int i = threadIdx.x; i < HB; i += blockDim.x) h[i] = 0;
    __syncthreads();
    const int stride = HBLK * blockDim.x;
    for (int i = blk * blockDim.x + threadIdx.x; i < E; i += stride) {
        int id = arr[i] - lo;
        if ((unsigned)id < (unsigned)HB) atomicAdd(&h[id], 1);   // LDS atomic
    }
    __syncthreads();
    unsigned short* __restrict__ out = partial + ((size_t)sec * HBLK + blk) * HB;
    for (int i = threadIdx.x; i < HB; i += blockDim.x) out[i] = (unsigned short)h[i];
}

// ---- reduce HBLK u16 partials/section -> cnt + norms ----
__global__ void reduce_norms2(const unsigned short* __restrict__ partial, int* __restrict__ cnt,
                              float* __restrict__ norms) {
    int stride = gridDim.x * blockDim.x;
    for (int i = blockIdx.x * blockDim.x + threadIdx.x; i < NTAB; i += stride) {
        int t = i / 50000;
        int r = i - t * 50000;
        int q = r / HB;
        int j = r - q * HB;
        const unsigned short* __restrict__ p = partial + ((size_t)(t * 4 + q) * HBLK) * HB + j;
        int s = 0;
#pragma unroll
        for (int b = 0; b < HBLK; ++b) s += p[(size_t)b * HB];
        cnt[i] = s;
        norms[i] = 1.0f / sqrtf((float)max(s, 1));
    }
}

// ---- parallel exclusive scan of the two dst-count tables, 3 phases ----
__global__ __launch_bounds__(256) void scanA(const int* __restrict__ cnt, int* __restrict__ bsum) {
    __shared__ int red[256];
    const int c = blockIdx.x;
    const int* __restrict__ cbl = cnt + ((c >= 100) ? 150000 : 50000);
    const int j0 = (c % 100) * CH;
    int s = 0;
    for (int i = threadIdx.x; i < CH; i += 256) s += cbl[j0 + i];
    red[threadIdx.x] = s;
    __syncthreads();
    for (int off = 128; off > 0; off >>= 1) {
        if (threadIdx.x < off) red[threadIdx.x] += red[threadIdx.x + off];
        __syncthreads();
    }
    if (threadIdx.x == 0) bsum[c] = red[0];
}

__global__ void scanB(const int* __restrict__ bsum, int* __restrict__ cbase) {
    __shared__ int b[200];
    for (int i = threadIdx.x; i < 200; i += blockDim.x) b[i] = bsum[i];
    __syncthreads();
    if (threadIdx.x < 2) {
        int run = 0;
        const int o = threadIdx.x * 100;
        for (int k = 0; k < 100; ++k) { cbase[o + k] = run; run += b[o + k]; }
    }
}

__global__ __launch_bounds__(512) void scanC(const int* __restrict__ cnt,
                                             const int* __restrict__ cbase,
                                             int* __restrict__ ptr_rc, int* __restrict__ ptr_cr,
                                             int E) {
    __shared__ int buf[512];
    const int c = blockIdx.x;
    const int table = (c >= 100);
    const int* __restrict__ cbl = cnt + (table ? 150000 : 50000);
    int* __restrict__ ptr = table ? ptr_cr : ptr_rc;
    const int j0 = (c % 100) * CH;
    const int t = threadIdx.x;
    const int v = (t < CH) ? cbl[j0 + t] : 0;
    buf[t] = v;
    __syncthreads();
    for (int off = 1; off < 512; off <<= 1) {
        int tmp = (t >= off) ? buf[t - off] : 0;
        __syncthreads();
        buf[t] += tmp;
        __syncthreads();
    }
    if (t < CH) ptr[j0 + t] = cbase[c] + buf[t] - v;
    if ((c % 100) == 99 && t == 0) ptr[50000] = E;
}

// ---- dst-section u16 partials -> absolute int block start positions ----
__global__ void block_starts(const unsigned short* __restrict__ partial, int* __restrict__ bstart,
                             const int* __restrict__ ptr_rc, const int* __restrict__ ptr_cr) {
    int stride = gridDim.x * blockDim.x;
    for (int i = blockIdx.x * blockDim.x + threadIdx.x; i < 8 * HB; i += stride) {
        int fsec = i / HB;                 // 0..7 = (rel, quarter)
        int j = i - fsec * HB;
        int rel = fsec >> 2, q = fsec & 3;
        int histsec = rel * 8 + 4 + q;     // dst tab = rel*2+1
        const int* __restrict__ ptr = rel ? ptr_cr : ptr_rc;
        int run = ptr[q * HB + j];
        const unsigned short* __restrict__ p = partial + ((size_t)histsec * HBLK) * HB + j;
        int* __restrict__ o = bstart + ((size_t)fsec * HBLK) * HB + j;
#pragma unroll
        for (int b = 0; b < HBLK; ++b) {
            o[(size_t)b * HB] = run;
            run += p[(size_t)b * HB];
        }
    }
}

// ---- CSR fill, XCD-affine (blockIdx%8 = section), LDS offsets, 4B packed pair ----
__global__ __launch_bounds__(512) void csr_fill_sorted(
        const int* __restrict__ sA, const int* __restrict__ dA,
        const float* __restrict__ wA, const float* __restrict__ routA, unsigned* __restrict__ pairA,
        const int* __restrict__ sB, const int* __restrict__ dB,
        const float* __restrict__ wB, const float* __restrict__ routB, unsigned* __restrict__ pairB,
        const int* __restrict__ bstart, int E) {
    __shared__ int offs[HB];
    const int fsec = blockIdx.x & 7;           // section -> XCD
    const int blk  = blockIdx.x >> 3;          // 0..63
    const int rel = fsec >> 2, q = fsec & 3;
    const int lo = q * HB;
    const int* __restrict__ src  = rel ? sB : sA;
    const int* __restrict__ dst  = rel ? dB : dA;
    const float* __restrict__ w  = rel ? wB : wA;
    const float* __restrict__ ro = rel ? routB : routA;
    unsigned* __restrict__ pair  = rel ? pairB : pairA;
    const int* __restrict__ bs = bstart + ((size_t)fsec * HBLK + blk) * HB;
    for (int i = threadIdx.x; i < HB; i += blockDim.x) offs[i] = bs[i];
    __syncthreads();
    const int stride = HBLK * blockDim.x;
    for (int i = blk * blockDim.x + threadIdx.x; i < E; i += stride) {
        int id = dst[i] - lo;
        if ((unsigned)id < (unsigned)HB) {
            int pos = atomicAdd(&offs[id], 1);            // LDS atomic
            int s = src[i];
            pair[pos] = (unsigned)s | ((unsigned)f2bf(w[i] * ro[s]) << 16);
        }
    }
}

// ---- fp32 -> fp8 feature tables + transposed bf16 weights, one launch ----
__global__ void prep_tables(const float4* __restrict__ fr, const float4* __restrict__ fc,
                            unsigned* __restrict__ f8r, unsigned* __restrict__ f8c, int nq,
                            const float* __restrict__ W0a, const float* __restrict__ W0b,
                            const float* __restrict__ W1a, const float* __restrict__ W1b,
                            unsigned short* __restrict__ wt) {
    const int total = 2 * nq + 49152;
    int stride = gridDim.x * blockDim.x;
    for (int i = blockIdx.x * blockDim.x + threadIdx.x; i < total; i += stride) {
        if (i < 2 * nq) {
            bool second = i >= nq;
            int k = second ? i - nq : i;
            float4 v = second ? fc[k] : fr[k];
            unsigned o = (unsigned)f2fp8(v.x) | ((unsigned)f2fp8(v.y) << 8)
                       | ((unsigned)f2fp8(v.z) << 16) | ((unsigned)f2fp8(v.w) << 24);
            if (second) f8c[k] = o; else f8r[k] = o;
        } else {
            int j = i - 2 * nq;
            const float* W; int K, base;
            if (j < 8192)       { W = W0a; K = 64;  base = 0; }
            else if (j < 16384) { W = W0b; K = 64;  base = 8192;  j -= 8192; }
            else if (j < 32768) { W = W1a; K = 128; base = 16384; j -= 16384; }
            else                { W = W1b; K = 128; base = 32768; j -= 32768; }
            int n = j / K, k = j - n * K;
            wt[base + n * K + k] = f2bf(W[k * DH + n]);
        }
    }
}

// ---- D=64 gather: quarter-wave per edge (16 lanes x 4B = full row), 4 edges/instr ----
__global__ void gather64_2(const uint8_t* __restrict__ hA, const int* __restrict__ ptrA,
                           const unsigned* __restrict__ pairA, unsigned short* __restrict__ aggA,
                           const uint8_t* __restrict__ hB, const int* __restrict__ ptrB,
                           const unsigned* __restrict__ pairB, unsigned short* __restrict__ aggB,
                           int n) {
    const int low  = blockIdx.x & 7;
    const int rel  = low >> 2;                  // XCDs 0-3: rel A, 4-7: rel B
    const int bid  = (blockIdx.x >> 3) * 4 + (low & 3);
    const uint8_t* __restrict__ h = rel ? hB : hA;
    const int* __restrict__ ptr  = rel ? ptrB : ptrA;
    const unsigned* __restrict__ pair = rel ? pairB : pairA;
    unsigned short* __restrict__ agg  = rel ? aggB : aggA;
    const int gw   = (bid * blockDim.x + threadIdx.x) >> 6;
    const int nw   = (GGRID * blockDim.x) >> 6;
    const int lane = threadIdx.x & 63;
    const int qtr  = lane >> 4;                 // 0..3: edge slot
    const unsigned coff = (unsigned)((lane & 15) << 2);   // byte/col base 0..60
    for (int node = gw; node < n; node += nw) {
        const int beg = ptr[node], end = ptr[node + 1];
        float a0[2] = {0.f, 0.f}, a1[2] = {0.f, 0.f}, a2[2] = {0.f, 0.f}, a3[2] = {0.f, 0.f};
        int j = beg + qtr;
        for (; j + 4 < end; j += 8) {           // 2 edges per quarter in flight
            unsigned p0 = pair[j], p1 = pair[j + 4];
            unsigned hv0 = *reinterpret_cast<const unsigned*>(&h[((p0 & 0xffffu) << 6) + coff]);
            unsigned hv1 = *reinterpret_cast<const unsigned*>(&h[((p1 & 0xffffu) << 6) + coff]);
            f32x4 d0 = fp8x4f(hv0), d1 = fp8x4f(hv1);
            float w0 = bf_hi(p0), w1 = bf_hi(p1);
            a0[0] = fmaf(d0.x, w0, a0[0]); a1[0] = fmaf(d0.y, w0, a1[0]);
            a2[0] = fmaf(d0.z, w0, a2[0]); a3[0] = fmaf(d0.w, w0, a3[0]);
            a0[1] = fmaf(d1.x, w1, a0[1]); a1[1] = fmaf(d1.y, w1, a1[1]);
            a2[1] = fmaf(d1.z, w1, a2[1]); a3[1] = fmaf(d1.w, w1, a3[1]);
        }
        for (; j < end; j += 4) {
            unsigned p = pair[j];
            unsigned hv = *reinterpret_cast<const unsigned*>(&h[((p & 0xffffu) << 6) + coff]);
            f32x4 d = fp8x4f(hv);
            float w = bf_hi(p);
            a0[0] = fmaf(d.x, w, a0[0]); a1[0] = fmaf(d.y, w, a1[0]);
            a2[0] = fmaf(d.z, w, a2[0]); a3[0] = fmaf(d.w, w, a3[0]);
        }
        float s0 = a0[0] + a0[1], s1 = a1[0] + a1[1];
        float s2 = a2[0] + a2[1], s3 = a3[0] + a3[1];
        s0 += __shfl_xor(s0, 16); s0 += __shfl_xor(s0, 32);
        s1 += __shfl_xor(s1, 16); s1 += __shfl_xor(s1, 32);
        s2 += __shfl_xor(s2, 16); s2 += __shfl_xor(s2, 32);
        s3 += __shfl_xor(s3, 16); s3 += __shfl_xor(s3, 32);
        if (lane < 16) {
            uint2 pk;
            pk.x = (unsigned)f2bf(s0) | ((unsigned)f2bf(s1) << 16);
            pk.y = (unsigned)f2bf(s2) | ((unsigned)f2bf(s3) << 16);
            *reinterpret_cast<uint2*>(&agg[(size_t)node * 64 + ((lane & 15) << 2)]) = pk;
        }
    }
}

// ---- layer-1 dense via MFMA 16x16x32 bf16, both relations fused ----
__global__ __launch_bounds__(256) void dense64_2(
        const unsigned short* __restrict__ aggA, const float* __restrict__ rinA,
        const unsigned short* __restrict__ wtA, const float* __restrict__ bA,
        unsigned short* __restrict__ outA,
        const unsigned short* __restrict__ aggB, const float* __restrict__ rinB,
        const unsigned short* __restrict__ wtB, const float* __restrict__ bB,
        unsigned short* __restrict__ outB, int n) {
    constexpr int K = 64, NCH = 2;
    const int rel = blockIdx.x >= DGRID;
    const int bid = rel ? blockIdx.x - DGRID : blockIdx.x;
    const unsigned short* __restrict__ agg = rel ? aggB : aggA;
    const float* __restrict__ rin = rel ? rinB : rinA;
    const unsigned short* __restrict__ wt = rel ? wtB : wtA;
    const float* __restrict__ b = rel ? bB : bA;
    unsigned short* __restrict__ outbf = rel ? outB : outA;

    const int wave = threadIdx.x >> 6;
    const int lane = threadIdx.x & 63;
    const int lrow = lane & 15;
    const int kgrp = lane >> 4;
    const int c0   = wave * 32;

    short8 bfr[2][NCH];
#pragma unroll
    for (int t = 0; t < 2; ++t)
#pragma unroll
        for (int ch = 0; ch < NCH; ++ch)
            bfr[t][ch] = *reinterpret_cast<const short8*>(
                &wt[(size_t)(c0 + t * 16 + lrow) * K + ch * 32 + kgrp * 8]);

    const float bias0 = b[c0 + lrow], bias1 = b[c0 + 16 + lrow];
    const int nstrip = n >> 4;
    for (int s = bid; s < nstrip; s += DGRID) {
        const int r0 = s << 4;
        f32x4 d0 = {0.f, 0.f, 0.f, 0.f}, d1 = {0.f, 0.f, 0.f, 0.f};
#pragma unroll
        for (int ch = 0; ch < NCH; ++ch) {
            short8 af = *reinterpret_cast<const short8*>(
                &agg[(size_t)(r0 + lrow) * K + ch * 32 + kgrp * 8]);
            d0 = __builtin_amdgcn_mfma_f32_16x16x32_bf16(af, bfr[0][ch], d0, 0, 0, 0);
            d1 = __builtin_amdgcn_mfma_f32_16x16x32_bf16(af, bfr[1][ch], d1, 0, 0, 0);
        }
#pragma unroll
        for (int i = 0; i < 4; ++i) {          // C/D: col=lane&15, row=(lane>>4)*4+i
            const int row = r0 + kgrp * 4 + i;
            const float rv = rin[row];
            outbf[(size_t)row * DH + c0 + lrow]      = f2bf(fmaxf(fmaf(rv, d0[i], bias0), 0.f));
            outbf[(size_t)row * DH + c0 + 16 + lrow] = f2bf(fmaxf(fmaf(rv, d1[i], bias1), 0.f));
        }
    }
}

// ---- h1t = h1 @ W1 -> fp8 tables (pre-transform; both relations fused) ----
__global__ __launch_bounds__(256) void h1t_gemm2(
        const unsigned short* __restrict__ hA, const unsigned short* __restrict__ wtA,
        uint8_t* __restrict__ htA,
        const unsigned short* __restrict__ hB, const unsigned short* __restrict__ wtB,
        uint8_t* __restrict__ htB, int n) {
    constexpr int K = 128, NCH = 4;
    const int rel = blockIdx.x >= DGRID;
    const int bid = rel ? blockIdx.x - DGRID : blockIdx.x;
    const unsigned short* __restrict__ h = rel ? hB : hA;
    const unsigned short* __restrict__ wt = rel ? wtB : wtA;
    uint8_t* __restrict__ ht = rel ? htB : htA;

    const int wave = threadIdx.x >> 6;
    const int lane = threadIdx.x & 63;
    const int lrow = lane & 15;
    const int kgrp = lane >> 4;
    const int c0   = wave * 32;

    short8 bfr[2][NCH];
#pragma unroll
    for (int t = 0; t < 2; ++t)
#pragma unroll
        for (int ch = 0; ch < NCH; ++ch)
            bfr[t][ch] = *reinterpret_cast<const short8*>(
                &wt[(size_t)(c0 + t * 16 + lrow) * K + ch * 32 + kgrp * 8]);

    const int nstrip = n >> 4;
    for (int s = bid; s < nstrip; s += DGRID) {
        const int r0 = s << 4;
        f32x4 d0 = {0.f, 0.f, 0.f, 0.f}, d1 = {0.f, 0.f, 0.f, 0.f};
#pragma unroll
        for (int ch = 0; ch < NCH; ++ch) {
            short8 af = *reinterpret_cast<const short8*>(
                &h[(size_t)(r0 + lrow) * K + ch * 32 + kgrp * 8]);
            d0 = __builtin_amdgcn_mfma_f32_16x16x32_bf16(af, bfr[0][ch], d0, 0, 0, 0);
            d1 = __builtin_amdgcn_mfma_f32_16x16x32_bf16(af, bfr[1][ch], d1, 0, 0, 0);
        }
#pragma unroll
        for (int i = 0; i < 4; ++i) {
            const int row = r0 + kgrp * 4 + i;
            ht[(size_t)row * DH + c0 + lrow]      = f2fp8(d0[i]);
            ht[(size_t)row * DH + c0 + 16 + lrow] = f2fp8(d1[i]);
        }
    }
}

// ---- final gather: XCD-affine (relation x col-half) so each L2 holds a 3.2MB slice;
//      half-wave per edge (32 lanes x 2B), fused relu + mean-pool (64-col partials) ----
__global__ __launch_bounds__(256) void gather_final(
        const uint8_t* __restrict__ htA, const int* __restrict__ ptrA,
        const unsigned* __restrict__ pairA, const float* __restrict__ rinA,
        const float* __restrict__ bA,
        const uint8_t* __restrict__ htB, const int* __restrict__ ptrB,
        const unsigned* __restrict__ pairB, const float* __restrict__ rinB,
        const float* __restrict__ bB,
        float* __restrict__ partsum, int n, float invn) {
    const int low  = blockIdx.x & 7;
    const int rel  = low >> 2;                  // bit2: relation
    const int chf  = (low >> 1) & 1;            // bit1: column half
    const int bid  = (blockIdx.x >> 3) * 2 + (low & 1);   // 0..1023 within combo
    const uint8_t* __restrict__ ht = rel ? htB : htA;
    const int* __restrict__ ptr  = rel ? ptrB : ptrA;
    const unsigned* __restrict__ pair = rel ? pairB : pairA;
    const float* __restrict__ rin = rel ? rinB : rinA;
    const float* __restrict__ b   = rel ? bB : bA;

    const int gw   = (bid * blockDim.x + threadIdx.x) >> 6;
    const int nw   = ((GGRID / 2) * blockDim.x) >> 6;       // 1024 blocks * 4 waves
    const int lane = threadIdx.x & 63;
    const int h2   = lane >> 5;                 // edge slot (0/1)
    const unsigned coff = (unsigned)(chf * 64 + ((lane & 31) << 1));
    const float b0v = b[coff], b1v = b[coff + 1];
    float m0 = 0.f, m1 = 0.f;

    for (int node = gw; node < n; node += nw) {
        const int beg = ptr[node], end = ptr[node + 1];
        float a0[4] = {0.f, 0.f, 0.f, 0.f}, a1[4] = {0.f, 0.f, 0.f, 0.f};
        int j = beg + h2;
        for (; j + 6 < end; j += 8) {           // 4 edges per half in flight
            unsigned p[4], hv[4];
#pragma unroll
            for (int u = 0; u < 4; ++u) p[u] = pair[j + 2 * u];
#pragma unroll
            for (int u = 0; u < 4; ++u)
                hv[u] = *reinterpret_cast<const unsigned short*>(&ht[((p[u] & 0xffffu) << 7) + coff]);
#pragma unroll
            for (int u = 0; u < 4; ++u) {
                f32x2 d = fp8x2f(hv[u]);
                float w = bf_hi(p[u]);
                a0[u] = fmaf(d.x, w, a0[u]);
                a1[u] = fmaf(d.y, w, a1[u]);
            }
        }
        for (; j < end; j += 2) {
            unsigned p = pair[j];
            unsigned hv = *reinterpret_cast<const unsigned short*>(&ht[((p & 0xffffu) << 7) + coff]);
            f32x2 d = fp8x2f(hv);
            float w = bf_hi(p);
            a0[0] = fmaf(d.x, w, a0[0]);
            a1[0] = fmaf(d.y, w, a1[0]);
        }
        float sx = (a0[0] + a0[1]) + (a0[2] + a0[3]);
        float sy = (a1[0] + a1[1]) + (a1[2] + a1[3]);
        sx += __shfl_xor(sx, 32);               // combine the two edge-halves
        sy += __shfl_xor(sy, 32);
        const float rv = rin[node];
        m0 += fmaxf(fmaf(rv, sx, b0v), 0.f);
        m1 += fmaxf(fmaf(rv, sy, b1v), 0.f);
    }

    __shared__ float red[4][64];
    const int wv = threadIdx.x >> 6;
    if (h2 == 0) {
        red[wv][(lane & 31) * 2]     = m0;
        red[wv][(lane & 31) * 2 + 1] = m1;
    }
    __syncthreads();
    if (threadIdx.x < 64) {
        float s = red[0][threadIdx.x] + red[1][threadIdx.x]
                + red[2][threadIdx.x] + red[3][threadIdx.x];
        partsum[(size_t)blockIdx.x * 64 + threadIdx.x] = s * invn;
    }
}

// ---- sum 64-col partials into out[0..127]; block b covers col-half (b>>1)&1 ----
__global__ void reduce_out2(const float* __restrict__ partsum, float* __restrict__ out, int nblk) {
    const int t = threadIdx.x;                 // 0..127; wave0 -> cols 0-63, wave1 -> 64-127
    const int ch = t >> 6, c = t & 63;
    float s = 0.f;
    for (int b = blockIdx.x; b < nblk; b += gridDim.x)
        if (((b >> 1) & 1) == ch) s += partsum[(size_t)b * 64 + c];
    atomicAdd(&out[t], s);
}

extern "C" void kernel_launch(void* const* d_in, const int* in_sizes, int n_in,
                              void* d_out, int out_size, void* d_ws, size_t ws_size,
                              hipStream_t stream) {
    const float* feat_row = (const float*)d_in[0];
    const float* feat_col = (const float*)d_in[1];
    const int*   src_rc   = (const int*)d_in[2];
    const int*   dst_rc   = (const int*)d_in[3];
    const float* w_rc     = (const float*)d_in[4];
    const int*   src_cr   = (const int*)d_in[5];
    const int*   dst_cr   = (const int*)d_in[6];
    const float* w_cr     = (const float*)d_in[7];
    const float* W0_rc    = (const float*)d_in[8];
    const float* b0_rc    = (const float*)d_in[9];
    const float* W0_cr    = (const float*)d_in[10];
    const float* b0_cr    = (const float*)d_in[11];
    const float* W1_rc    = (const float*)d_in[12];
    const float* b1_rc    = (const float*)d_in[13];
    const float* W1_cr    = (const float*)d_in[14];
    const float* b1_cr    = (const float*)d_in[15];
    const int E = in_sizes[2];
    float* out = (float*)d_out;

    // ---- workspace layout (~75 MB) ----
    int*   cnt     = (int*)d_ws;                        // 200000
    float* norms   = (float*)(cnt + 200000);            // 200000
    int*   ptr_rc  = (int*)(norms + 200000);            // 50004
    int*   ptr_cr  = ptr_rc + 50004;                    // 50004
    int*   bsum    = ptr_cr + 50004;                    // 200
    int*   cbase   = bsum + 200;                        // 216 (pad)
    unsigned* pair_rc = (unsigned*)(cbase + 216);       // E
    unsigned* pair_cr = pair_rc + E;                    // E
    unsigned short* agg_col = (unsigned short*)(pair_cr + E);       // 50000*64 bf16
    unsigned short* agg_row = agg_col + (size_t)NCOL * 64;          // 50000*64 bf16
    uint8_t* f8_row = (uint8_t*)(agg_row + (size_t)NROW * 64);      // 50000*64 fp8
    uint8_t* f8_col = f8_row + (size_t)NROW * 64;                   // 50000*64 fp8
    unsigned short* h_col1 = (unsigned short*)(f8_col + (size_t)NCOL * 64); // 50000*128 bf16
    unsigned short* h_row1 = h_col1 + (size_t)NCOL * DH;                    // 50000*128 bf16
    uint8_t* ht_row = (uint8_t*)(h_row1 + (size_t)NROW * DH);       // 50000*128 fp8
    uint8_t* ht_col = ht_row + (size_t)NROW * DH;                   // 50000*128 fp8
    float* partsum = (float*)(ht_col + (size_t)NCOL * DH);          // 2*GGRID*64 fp32
    unsigned short* wt = (unsigned short*)(partsum + (size_t)2 * GGRID * DH); // 49152
    // CSR-build aliases (dead before gathers/prep): u16 partial (25.6 MB) + int bstart (25.6 MB)
    unsigned short* partial = (unsigned short*)agg_col;             // 16*HBLK*HB u16
    int* bstart = (int*)(partial + (size_t)16 * HBLK * HB);         // 8*HBLK*HB int

    float* r_out_rc = norms;
    float* r_in_rc  = norms + NROW;
    float* r_out_cr = norms + NROW + NCOL;
    float* r_in_cr  = norms + NROW + 2 * NCOL;

    unsigned short* wt0_rc = wt;
    unsigned short* wt0_cr = wt + 8192;
    unsigned short* wt1_rc = wt + 16384;
    unsigned short* wt1_cr = wt + 32768;

    // ---- CSR build (aliases live here) ----
    hist_lds<<<16 * HBLK, 512, 0, stream>>>(src_rc, dst_rc, src_cr, dst_cr, partial, E);
    reduce_norms2<<<512, 256, 0, stream>>>(partial, cnt, norms);
    scanA<<<200, 256, 0, stream>>>(cnt, bsum);
    scanB<<<1, 256, 0, stream>>>(bsum, cbase);
    scanC<<<200, 512, 0, stream>>>(cnt, cbase, ptr_rc, ptr_cr, E);
    block_starts<<<400, 256, 0, stream>>>(partial, bstart, ptr_rc, ptr_cr);
    csr_fill_sorted<<<8 * HBLK, 512, 0, stream>>>(
        src_rc, dst_rc, w_rc, r_out_rc, pair_rc,
        src_cr, dst_cr, w_cr, r_out_cr, pair_cr, bstart, E);

    // ---- fp8 feature tables + bf16 weights (aliases now dead) ----
    prep_tables<<<2048, 256, 0, stream>>>((const float4*)feat_row, (const float4*)feat_col,
                                          (unsigned*)f8_row, (unsigned*)f8_col, NROW * 64 / 4,
                                          W0_rc, W0_cr, W1_rc, W1_cr, wt);

    // ---- layer 1 ----
    gather64_2<<<2 * GGRID, 256, 0, stream>>>(f8_row, ptr_rc, pair_rc, agg_col,
                                              f8_col, ptr_cr, pair_cr, agg_row, NCOL);
    dense64_2<<<2 * DGRID, 256, 0, stream>>>(agg_col, r_in_rc, wt0_rc, b0_rc, h_col1,
                                             agg_row, r_in_cr, wt0_cr, b0_cr, h_row1, NCOL);

    // ---- layer 2: pre-transform h1@W1 -> fp8, then fused gather+relu+mean ----
    h1t_gemm2<<<2 * DGRID, 256, 0, stream>>>(h_row1, wt1_rc, ht_row,
                                             h_col1, wt1_cr, ht_col, NROW);
    hipMemsetAsync(out, 0, DH * sizeof(float), stream);
    gather_final<<<2 * GGRID, 256, 0, stream>>>(
        ht_row, ptr_rc, pair_rc, r_in_rc, b1_rc,
        ht_col, ptr_cr, pair_cr, r_in_cr, b1_cr,
        partsum, NCOL, 1.0f / NCOL);
    reduce_out2<<<64, 128, 0, stream>>>(partsum, out, 2 * GGRID);
}

// Round 16
// 336.197 us; speedup vs baseline: 1.0322x; 1.0322x over previous
//
#include <hip/hip_runtime.h>
#include <stdint.h>

constexpr int NROW = 50000;
constexpr int NCOL = 50000;
constexpr int DH   = 128;
constexpr int NTAB = 200000;   // [out_rc(NROW) | in_rc(NCOL) | out_cr(NCOL) | in_cr(NROW)]
constexpr int HB   = 12500;    // bins per section (quarter table), 50 KB LDS
constexpr int HBLK = 64;       // blocks per section
constexpr int DGRID = 1250;    // dense blocks per relation
constexpr int GGRID = 2048;    // gather blocks per relation
constexpr int CH    = 500;     // scan chunk size (100 chunks per table)

typedef __attribute__((ext_vector_type(8))) short short8;
typedef __attribute__((ext_vector_type(4))) float f32x4;
typedef __attribute__((ext_vector_type(2))) float f32x2;

__device__ __forceinline__ float bf_hi(unsigned u) { return __uint_as_float(u & 0xffff0000u); }
__device__ __forceinline__ unsigned short f2bf(float f) {   // RNE
    unsigned u = __float_as_uint(f);
    return (unsigned short)((u + 0x7fffu + ((u >> 16) & 1u)) >> 16);
}

// ---- fp8 OCP e4m3fn encode (RNE, clamp 448, subnormal-aware) ----
__device__ __forceinline__ unsigned char f2fp8(float f) {
    unsigned b = __float_as_uint(f);
    unsigned s = (b >> 24) & 0x80u;
    unsigned mag = b & 0x7fffffffu;
    if (mag >= 0x43e00000u) return (unsigned char)(s | 0x7eu);   // clamp to ±448
    unsigned r = mag + 0x7ffffu + ((mag >> 20) & 1u);
    int e = (int)(r >> 23) - 120;
    if (e < 1) {                                                  // subnormal: m * 2^-9
        float af = __uint_as_float(mag);
        unsigned m = (unsigned)(af * 512.f + 0.5f);
        if (m > 8u) m = 8u;
        return (unsigned char)(s | m);
    }
    return (unsigned char)(s | (unsigned)(e << 3) | ((r >> 20) & 7u));
}

// ---- fp8 decode helpers (HW cvt if available) ----
#if defined(__has_builtin) && __has_builtin(__builtin_amdgcn_cvt_pk_f32_fp8)
__device__ __forceinline__ f32x2 fp8x2f(unsigned v) {
    return __builtin_amdgcn_cvt_pk_f32_fp8((int)v, false);
}
#else
__device__ __forceinline__ float fp8_1(unsigned u) {
    unsigned s = (u & 0x80u) << 24, em = u & 0x7fu;
    if (em >= 8u) return __uint_as_float(s | ((em + 960u) << 20));
    float v = (float)em * 0.001953125f;
    return (u & 0x80u) ? -v : v;
}
__device__ __forceinline__ f32x2 fp8x2f(unsigned v) {
    f32x2 r; r.x = fp8_1(v & 0xffu); r.y = fp8_1((v >> 8) & 0xffu); return r;
}
#endif

// ---- degree histograms via LDS privatization; u16 partials (max/block 18750) ----
__global__ __launch_bounds__(512) void hist_lds(
        const int* __restrict__ s_rc, const int* __restrict__ d_rc,
        const int* __restrict__ s_cr, const int* __restrict__ d_cr,
        unsigned short* __restrict__ partial, int E) {
    __shared__ int h[HB];
    const int sec = blockIdx.x >> 6;           // 0..15
    const int blk = blockIdx.x & (HBLK - 1);
    const int tab = sec >> 2;                  // 0..3 -> array
    const int lo  = (sec & 3) * HB;
    const int* __restrict__ arr = (tab == 0) ? s_rc : (tab == 1) ? d_rc
                                 : (tab == 2) ? s_cr : d_cr;
    for (int i = threadIdx.x; i < HB; i += blockDim.x) h[i] = 0;
    __syncthreads();
    const int stride = HBLK * blockDim.x;
    for (int i = blk * blockDim.x + threadIdx.x; i < E; i += stride) {
        int id = arr[i] - lo;
        if ((unsigned)id < (unsigned)HB) atomicAdd(&h[id], 1);   // LDS atomic
    }
    __syncthreads();
    unsigned short* __restrict__ out = partial + ((size_t)sec * HBLK + blk) * HB;
    for (int i = threadIdx.x; i < HB; i += blockDim.x) out[i] = (unsigned short)h[i];
}

// ---- reduce HBLK u16 partials/section -> cnt + norms ----
__global__ void reduce_norms2(const unsigned short* __restrict__ partial, int* __restrict__ cnt,
                              float* __restrict__ norms) {
    int stride = gridDim.x * blockDim.x;
    for (int i = blockIdx.x * blockDim.x + threadIdx.x; i < NTAB; i += stride) {
        int t = i / 50000;
        int r = i - t * 50000;
        int q = r / HB;
        int j = r - q * HB;
        const unsigned short* __restrict__ p = partial + ((size_t)(t * 4 + q) * HBLK) * HB + j;
        int s = 0;
#pragma unroll
        for (int b = 0; b < HBLK; ++b) s += p[(size_t)b * HB];
        cnt[i] = s;
        norms[i] = 1.0f / sqrtf((float)max(s, 1));
    }
}

// ---- parallel exclusive scan of the two dst-count tables, 3 phases ----
__global__ __launch_bounds__(256) void scanA(const int* __restrict__ cnt, int* __restrict__ bsum) {
    __shared__ int red[256];
    const int c = blockIdx.x;
    const int* __restrict__ cbl = cnt + ((c >= 100) ? 150000 : 50000);
    const int j0 = (c % 100) * CH;
    int s = 0;
    for (int i = threadIdx.x; i < CH; i += 256) s += cbl[j0 + i];
    red[threadIdx.x] = s;
    __syncthreads();
    for (int off = 128; off > 0; off >>= 1) {
        if (threadIdx.x < off) red[threadIdx.x] += red[threadIdx.x + off];
        __syncthreads();
    }
    if (threadIdx.x == 0) bsum[c] = red[0];
}

__global__ void scanB(const int* __restrict__ bsum, int* __restrict__ cbase) {
    __shared__ int b[200];
    for (int i = threadIdx.x; i < 200; i += blockDim.x) b[i] = bsum[i];
    __syncthreads();
    if (threadIdx.x < 2) {
        int run = 0;
        const int o = threadIdx.x * 100;
        for (int k = 0; k < 100; ++k) { cbase[o + k] = run; run += b[o + k]; }
    }
}

__global__ __launch_bounds__(512) void scanC(const int* __restrict__ cnt,
                                             const int* __restrict__ cbase,
                                             int* __restrict__ ptr_rc, int* __restrict__ ptr_cr,
                                             int E) {
    __shared__ int buf[512];
    const int c = blockIdx.x;
    const int table = (c >= 100);
    const int* __restrict__ cbl = cnt + (table ? 150000 : 50000);
    int* __restrict__ ptr = table ? ptr_cr : ptr_rc;
    const int j0 = (c % 100) * CH;
    const int t = threadIdx.x;
    const int v = (t < CH) ? cbl[j0 + t] : 0;
    buf[t] = v;
    __syncthreads();
    for (int off = 1; off < 512; off <<= 1) {
        int tmp = (t >= off) ? buf[t - off] : 0;
        __syncthreads();
        buf[t] += tmp;
        __syncthreads();
    }
    if (t < CH) ptr[j0 + t] = cbase[c] + buf[t] - v;
    if ((c % 100) == 99 && t == 0) ptr[50000] = E;
}

// ---- dst-section u16 partials -> absolute int block start positions ----
__global__ void block_starts(const unsigned short* __restrict__ partial, int* __restrict__ bstart,
                             const int* __restrict__ ptr_rc, const int* __restrict__ ptr_cr) {
    int stride = gridDim.x * blockDim.x;
    for (int i = blockIdx.x * blockDim.x + threadIdx.x; i < 8 * HB; i += stride) {
        int fsec = i / HB;                 // 0..7 = (rel, quarter)
        int j = i - fsec * HB;
        int rel = fsec >> 2, q = fsec & 3;
        int histsec = rel * 8 + 4 + q;     // dst tab = rel*2+1
        const int* __restrict__ ptr = rel ? ptr_cr : ptr_rc;
        int run = ptr[q * HB + j];
        const unsigned short* __restrict__ p = partial + ((size_t)histsec * HBLK) * HB + j;
        int* __restrict__ o = bstart + ((size_t)fsec * HBLK) * HB + j;
#pragma unroll
        for (int b = 0; b < HBLK; ++b) {
            o[(size_t)b * HB] = run;
            run += p[(size_t)b * HB];
        }
    }
}

// ---- CSR fill, XCD-affine (blockIdx%8 = section), LDS offsets, 4B packed pair ----
__global__ __launch_bounds__(512) void csr_fill_sorted(
        const int* __restrict__ sA, const int* __restrict__ dA,
        const float* __restrict__ wA, const float* __restrict__ routA, unsigned* __restrict__ pairA,
        const int* __restrict__ sB, const int* __restrict__ dB,
        const float* __restrict__ wB, const float* __restrict__ routB, unsigned* __restrict__ pairB,
        const int* __restrict__ bstart, int E) {
    __shared__ int offs[HB];
    const int fsec = blockIdx.x & 7;           // section -> XCD
    const int blk  = blockIdx.x >> 3;          // 0..63
    const int rel = fsec >> 2, q = fsec & 3;
    const int lo = q * HB;
    const int* __restrict__ src  = rel ? sB : sA;
    const int* __restrict__ dst  = rel ? dB : dA;
    const float* __restrict__ w  = rel ? wB : wA;
    const float* __restrict__ ro = rel ? routB : routA;
    unsigned* __restrict__ pair  = rel ? pairB : pairA;
    const int* __restrict__ bs = bstart + ((size_t)fsec * HBLK + blk) * HB;
    for (int i = threadIdx.x; i < HB; i += blockDim.x) offs[i] = bs[i];
    __syncthreads();
    const int stride = HBLK * blockDim.x;
    for (int i = blk * blockDim.x + threadIdx.x; i < E; i += stride) {
        int id = dst[i] - lo;
        if ((unsigned)id < (unsigned)HB) {
            int pos = atomicAdd(&offs[id], 1);            // LDS atomic
            int s = src[i];
            pair[pos] = (unsigned)s | ((unsigned)f2bf(w[i] * ro[s]) << 16);
        }
    }
}

// ---- fp32 -> fp8 feature tables + transposed bf16 weights, one launch ----
__global__ void prep_tables(const float4* __restrict__ fr, const float4* __restrict__ fc,
                            unsigned* __restrict__ f8r, unsigned* __restrict__ f8c, int nq,
                            const float* __restrict__ W0a, const float* __restrict__ W0b,
                            const float* __restrict__ W1a, const float* __restrict__ W1b,
                            unsigned short* __restrict__ wt) {
    const int total = 2 * nq + 49152;
    int stride = gridDim.x * blockDim.x;
    for (int i = blockIdx.x * blockDim.x + threadIdx.x; i < total; i += stride) {
        if (i < 2 * nq) {
            bool second = i >= nq;
            int k = second ? i - nq : i;
            float4 v = second ? fc[k] : fr[k];
            unsigned o = (unsigned)f2fp8(v.x) | ((unsigned)f2fp8(v.y) << 8)
                       | ((unsigned)f2fp8(v.z) << 16) | ((unsigned)f2fp8(v.w) << 24);
            if (second) f8c[k] = o; else f8r[k] = o;
        } else {
            int j = i - 2 * nq;
            const float* W; int K, base;
            if (j < 8192)       { W = W0a; K = 64;  base = 0; }
            else if (j < 16384) { W = W0b; K = 64;  base = 8192;  j -= 8192; }
            else if (j < 32768) { W = W1a; K = 128; base = 16384; j -= 16384; }
            else                { W = W1b; K = 128; base = 32768; j -= 32768; }
            int n = j / K, k = j - n * K;
            wt[base + n * K + k] = f2bf(W[k * DH + n]);
        }
    }
}

// ---- D=64 gather from fp8 tables, XCD-affine relation split, 8 edges/half in flight ----
__global__ void gather64_2(const uint8_t* __restrict__ hA, const int* __restrict__ ptrA,
                           const unsigned* __restrict__ pairA, unsigned short* __restrict__ aggA,
                           const uint8_t* __restrict__ hB, const int* __restrict__ ptrB,
                           const unsigned* __restrict__ pairB, unsigned short* __restrict__ aggB,
                           int n) {
    const int low  = blockIdx.x & 7;
    const int rel  = low >> 2;                  // XCDs 0-3: rel A, 4-7: rel B
    const int bid  = (blockIdx.x >> 3) * 4 + (low & 3);
    const uint8_t* __restrict__ h = rel ? hB : hA;
    const int* __restrict__ ptr  = rel ? ptrB : ptrA;
    const unsigned* __restrict__ pair = rel ? pairB : pairA;
    unsigned short* __restrict__ agg  = rel ? aggB : aggA;
    const int gw   = (bid * blockDim.x + threadIdx.x) >> 6;
    const int nw   = (GGRID * blockDim.x) >> 6;
    const int lane = threadIdx.x & 63;
    const int half = lane >> 5;
    const int c    = (lane & 31) << 1;          // column pair 0..62 (byte offset too)
    for (int node = gw; node < n; node += nw) {
        const int beg = ptr[node], end = ptr[node + 1];
        float ax[8], ay[8];
#pragma unroll
        for (int u = 0; u < 8; ++u) { ax[u] = 0.f; ay[u] = 0.f; }
        int j = beg + half;
        for (; j + 14 < end; j += 16) {         // 8 edges per half-wave in flight
            unsigned p[8], hv[8];
#pragma unroll
            for (int u = 0; u < 8; ++u) p[u] = pair[j + 2 * u];
#pragma unroll
            for (int u = 0; u < 8; ++u)
                hv[u] = *reinterpret_cast<const unsigned short*>(&h[((p[u] & 0xffffu) << 6) + c]);
#pragma unroll
            for (int u = 0; u < 8; ++u) {
                f32x2 d = fp8x2f(hv[u]);
                float w = bf_hi(p[u]);
                ax[u] = fmaf(d.x, w, ax[u]); ay[u] = fmaf(d.y, w, ay[u]);
            }
        }
        for (; j < end; j += 2) {
            unsigned p = pair[j];
            unsigned hv = *reinterpret_cast<const unsigned short*>(&h[((p & 0xffffu) << 6) + c]);
            f32x2 d = fp8x2f(hv);
            float w = bf_hi(p);
            ax[0] = fmaf(d.x, w, ax[0]); ay[0] = fmaf(d.y, w, ay[0]);
        }
        float ax_ = ((ax[0] + ax[1]) + (ax[2] + ax[3])) + ((ax[4] + ax[5]) + (ax[6] + ax[7]));
        float ay_ = ((ay[0] + ay[1]) + (ay[2] + ay[3])) + ((ay[4] + ay[5]) + (ay[6] + ay[7]));
        ax_ += __shfl_xor(ax_, 32);
        ay_ += __shfl_xor(ay_, 32);
        if (half == 0) {
            unsigned pk = (unsigned)f2bf(ax_) | ((unsigned)f2bf(ay_) << 16);
            *reinterpret_cast<unsigned*>(&agg[(size_t)node * 64 + c]) = pk;
        }
    }
}

// ---- layer-1 dense via MFMA 16x16x32 bf16, both relations fused ----
__global__ __launch_bounds__(256) void dense64_2(
        const unsigned short* __restrict__ aggA, const float* __restrict__ rinA,
        const unsigned short* __restrict__ wtA, const float* __restrict__ bA,
        unsigned short* __restrict__ outA,
        const unsigned short* __restrict__ aggB, const float* __restrict__ rinB,
        const unsigned short* __restrict__ wtB, const float* __restrict__ bB,
        unsigned short* __restrict__ outB, int n) {
    constexpr int K = 64, NCH = 2;
    const int rel = blockIdx.x >= DGRID;
    const int bid = rel ? blockIdx.x - DGRID : blockIdx.x;
    const unsigned short* __restrict__ agg = rel ? aggB : aggA;
    const float* __restrict__ rin = rel ? rinB : rinA;
    const unsigned short* __restrict__ wt = rel ? wtB : wtA;
    const float* __restrict__ b = rel ? bB : bA;
    unsigned short* __restrict__ outbf = rel ? outB : outA;

    const int wave = threadIdx.x >> 6;
    const int lane = threadIdx.x & 63;
    const int lrow = lane & 15;
    const int kgrp = lane >> 4;
    const int c0   = wave * 32;

    short8 bfr[2][NCH];
#pragma unroll
    for (int t = 0; t < 2; ++t)
#pragma unroll
        for (int ch = 0; ch < NCH; ++ch)
            bfr[t][ch] = *reinterpret_cast<const short8*>(
                &wt[(size_t)(c0 + t * 16 + lrow) * K + ch * 32 + kgrp * 8]);

    const float bias0 = b[c0 + lrow], bias1 = b[c0 + 16 + lrow];
    const int nstrip = n >> 4;
    for (int s = bid; s < nstrip; s += DGRID) {
        const int r0 = s << 4;
        f32x4 d0 = {0.f, 0.f, 0.f, 0.f}, d1 = {0.f, 0.f, 0.f, 0.f};
#pragma unroll
        for (int ch = 0; ch < NCH; ++ch) {
            short8 af = *reinterpret_cast<const short8*>(
                &agg[(size_t)(r0 + lrow) * K + ch * 32 + kgrp * 8]);
            d0 = __builtin_amdgcn_mfma_f32_16x16x32_bf16(af, bfr[0][ch], d0, 0, 0, 0);
            d1 = __builtin_amdgcn_mfma_f32_16x16x32_bf16(af, bfr[1][ch], d1, 0, 0, 0);
        }
#pragma unroll
        for (int i = 0; i < 4; ++i) {          // C/D: col=lane&15, row=(lane>>4)*4+i
            const int row = r0 + kgrp * 4 + i;
            const float rv = rin[row];
            outbf[(size_t)row * DH + c0 + lrow]      = f2bf(fmaxf(fmaf(rv, d0[i], bias0), 0.f));
            outbf[(size_t)row * DH + c0 + 16 + lrow] = f2bf(fmaxf(fmaf(rv, d1[i], bias1), 0.f));
        }
    }
}

// ---- h1t = h1 @ W1 -> SPLIT fp8 half-tables (cols 0-63 -> ht0, 64-127 -> ht1) ----
__global__ __launch_bounds__(256) void h1t_gemm2(
        const unsigned short* __restrict__ hA, const unsigned short* __restrict__ wtA,
        uint8_t* __restrict__ htA0, uint8_t* __restrict__ htA1,
        const unsigned short* __restrict__ hB, const unsigned short* __restrict__ wtB,
        uint8_t* __restrict__ htB0, uint8_t* __restrict__ htB1, int n) {
    constexpr int K = 128, NCH = 4;
    const int rel = blockIdx.x >= DGRID;
    const int bid = rel ? blockIdx.x - DGRID : blockIdx.x;
    const unsigned short* __restrict__ h = rel ? hB : hA;
    const unsigned short* __restrict__ wt = rel ? wtB : wtA;

    const int wave = threadIdx.x >> 6;
    const int lane = threadIdx.x & 63;
    const int lrow = lane & 15;
    const int kgrp = lane >> 4;
    const int c0   = wave * 32;                 // 0,32 -> half 0; 64,96 -> half 1
    uint8_t* __restrict__ ht = (wave < 2) ? (rel ? htB0 : htA0) : (rel ? htB1 : htA1);
    const int cb = c0 & 63;                     // column base within half-table

    short8 bfr[2][NCH];
#pragma unroll
    for (int t = 0; t < 2; ++t)
#pragma unroll
        for (int ch = 0; ch < NCH; ++ch)
            bfr[t][ch] = *reinterpret_cast<const short8*>(
                &wt[(size_t)(c0 + t * 16 + lrow) * K + ch * 32 + kgrp * 8]);

    const int nstrip = n >> 4;
    for (int s = bid; s < nstrip; s += DGRID) {
        const int r0 = s << 4;
        f32x4 d0 = {0.f, 0.f, 0.f, 0.f}, d1 = {0.f, 0.f, 0.f, 0.f};
#pragma unroll
        for (int ch = 0; ch < NCH; ++ch) {
            short8 af = *reinterpret_cast<const short8*>(
                &h[(size_t)(r0 + lrow) * K + ch * 32 + kgrp * 8]);
            d0 = __builtin_amdgcn_mfma_f32_16x16x32_bf16(af, bfr[0][ch], d0, 0, 0, 0);
            d1 = __builtin_amdgcn_mfma_f32_16x16x32_bf16(af, bfr[1][ch], d1, 0, 0, 0);
        }
#pragma unroll
        for (int i = 0; i < 4; ++i) {
            const int row = r0 + kgrp * 4 + i;
            ht[((size_t)row << 6) + cb + lrow]      = f2fp8(d0[i]);
            ht[((size_t)row << 6) + cb + 16 + lrow] = f2fp8(d1[i]);
        }
    }
}

// ---- final gather: XCD-affine (relation x col-half); SPLIT 3.2MB half-tables
//      (64B rows, L2-resident per XCD); half-wave per edge; fused relu+mean ----
__global__ __launch_bounds__(256) void gather_final(
        const uint8_t* __restrict__ htA0, const uint8_t* __restrict__ htA1,
        const int* __restrict__ ptrA, const unsigned* __restrict__ pairA,
        const float* __restrict__ rinA, const float* __restrict__ bA,
        const uint8_t* __restrict__ htB0, const uint8_t* __restrict__ htB1,
        const int* __restrict__ ptrB, const unsigned* __restrict__ pairB,
        const float* __restrict__ rinB, const float* __restrict__ bB,
        float* __restrict__ partsum, int n, float invn) {
    const int low  = blockIdx.x & 7;
    const int rel  = low >> 2;                  // bit2: relation
    const int chf  = (low >> 1) & 1;            // bit1: column half
    const int bid  = (blockIdx.x >> 3) * 2 + (low & 1);   // 0..1023 within combo
    const uint8_t* __restrict__ ht = rel ? (chf ? htB1 : htB0) : (chf ? htA1 : htA0);
    const int* __restrict__ ptr  = rel ? ptrB : ptrA;
    const unsigned* __restrict__ pair = rel ? pairB : pairA;
    const float* __restrict__ rin = rel ? rinB : rinA;
    const float* __restrict__ b   = rel ? bB : bA;

    const int gw   = (bid * blockDim.x + threadIdx.x) >> 6;
    const int nw   = ((GGRID / 2) * blockDim.x) >> 6;       // 1024 blocks * 4 waves
    const int lane = threadIdx.x & 63;
    const int h2   = lane >> 5;                 // edge slot (0/1)
    const unsigned coff = (unsigned)((lane & 31) << 1);     // byte offset in 64B row
    const float b0v = b[chf * 64 + coff], b1v = b[chf * 64 + coff + 1];
    float m0 = 0.f, m1 = 0.f;

    for (int node = gw; node < n; node += nw) {
        const int beg = ptr[node], end = ptr[node + 1];
        float a0[4] = {0.f, 0.f, 0.f, 0.f}, a1[4] = {0.f, 0.f, 0.f, 0.f};
        int j = beg + h2;
        for (; j + 6 < end; j += 8) {           // 4 edges per half in flight
            unsigned p[4], hv[4];
#pragma unroll
            for (int u = 0; u < 4; ++u) p[u] = pair[j + 2 * u];
#pragma unroll
            for (int u = 0; u < 4; ++u)
                hv[u] = *reinterpret_cast<const unsigned short*>(&ht[((p[u] & 0xffffu) << 6) + coff]);
#pragma unroll
            for (int u = 0; u < 4; ++u) {
                f32x2 d = fp8x2f(hv[u]);
                float w = bf_hi(p[u]);
                a0[u] = fmaf(d.x, w, a0[u]);
                a1[u] = fmaf(d.y, w, a1[u]);
            }
        }
        for (; j < end; j += 2) {
            unsigned p = pair[j];
            unsigned hv = *reinterpret_cast<const unsigned short*>(&ht[((p & 0xffffu) << 6) + coff]);
            f32x2 d = fp8x2f(hv);
            float w = bf_hi(p);
            a0[0] = fmaf(d.x, w, a0[0]);
            a1[0] = fmaf(d.y, w, a1[0]);
        }
        float sx = (a0[0] + a0[1]) + (a0[2] + a0[3]);
        float sy = (a1[0] + a1[1]) + (a1[2] + a1[3]);
        sx += __shfl_xor(sx, 32);               // combine the two edge-halves
        sy += __shfl_xor(sy, 32);
        const float rv = rin[node];
        m0 += fmaxf(fmaf(rv, sx, b0v), 0.f);
        m1 += fmaxf(fmaf(rv, sy, b1v), 0.f);
    }

    __shared__ float red[4][64];
    const int wv = threadIdx.x >> 6;
    if (h2 == 0) {
        red[wv][(lane & 31) * 2]     = m0;
        red[wv][(lane & 31) * 2 + 1] = m1;
    }
    __syncthreads();
    if (threadIdx.x < 64) {
        float s = red[0][threadIdx.x] + red[1][threadIdx.x]
                + red[2][threadIdx.x] + red[3][threadIdx.x];
        partsum[(size_t)blockIdx.x * 64 + threadIdx.x] = s * invn;
    }
}

// ---- sum 64-col partials into out[0..127]; block b covers col-half (b>>1)&1 ----
__global__ void reduce_out2(const float* __restrict__ partsum, float* __restrict__ out, int nblk) {
    const int t = threadIdx.x;                 // 0..127; wave0 -> cols 0-63, wave1 -> 64-127
    const int ch = t >> 6, c = t & 63;
    float s = 0.f;
    for (int b = blockIdx.x; b < nblk; b += gridDim.x)
        if (((b >> 1) & 1) == ch) s += partsum[(size_t)b * 64 + c];
    atomicAdd(&out[t], s);
}

extern "C" void kernel_launch(void* const* d_in, const int* in_sizes, int n_in,
                              void* d_out, int out_size, void* d_ws, size_t ws_size,
                              hipStream_t stream) {
    const float* feat_row = (const float*)d_in[0];
    const float* feat_col = (const float*)d_in[1];
    const int*   src_rc   = (const int*)d_in[2];
    const int*   dst_rc   = (const int*)d_in[3];
    const float* w_rc     = (const float*)d_in[4];
    const int*   src_cr   = (const int*)d_in[5];
    const int*   dst_cr   = (const int*)d_in[6];
    const float* w_cr     = (const float*)d_in[7];
    const float* W0_rc    = (const float*)d_in[8];
    const float* b0_rc    = (const float*)d_in[9];
    const float* W0_cr    = (const float*)d_in[10];
    const float* b0_cr    = (const float*)d_in[11];
    const float* W1_rc    = (const float*)d_in[12];
    const float* b1_rc    = (const float*)d_in[13];
    const float* W1_cr    = (const float*)d_in[14];
    const float* b1_cr    = (const float*)d_in[15];
    const int E = in_sizes[2];
    float* out = (float*)d_out;

    // ---- workspace layout (~75 MB) ----
    int*   cnt     = (int*)d_ws;                        // 200000
    float* norms   = (float*)(cnt + 200000);            // 200000
    int*   ptr_rc  = (int*)(norms + 200000);            // 50004
    int*   ptr_cr  = ptr_rc + 50004;                    // 50004
    int*   bsum    = ptr_cr + 50004;                    // 200
    int*   cbase   = bsum + 200;                        // 216 (pad)
    unsigned* pair_rc = (unsigned*)(cbase + 216);       // E
    unsigned* pair_cr = pair_rc + E;                    // E
    unsigned short* agg_col = (unsigned short*)(pair_cr + E);       // 50000*64 bf16
    unsigned short* agg_row = agg_col + (size_t)NCOL * 64;          // 50000*64 bf16
    uint8_t* f8_row = (uint8_t*)(agg_row + (size_t)NROW * 64);      // 50000*64 fp8
    uint8_t* f8_col = f8_row + (size_t)NROW * 64;                   // 50000*64 fp8
    unsigned short* h_col1 = (unsigned short*)(f8_col + (size_t)NCOL * 64); // 50000*128 bf16
    unsigned short* h_row1 = h_col1 + (size_t)NCOL * DH;                    // 50000*128 bf16
    uint8_t* ht_row0 = (uint8_t*)(h_row1 + (size_t)NROW * DH);      // 50000*64 fp8
    uint8_t* ht_row1 = ht_row0 + (size_t)NROW * 64;                 // 50000*64 fp8
    uint8_t* ht_col0 = ht_row1 + (size_t)NROW * 64;                 // 50000*64 fp8
    uint8_t* ht_col1 = ht_col0 + (size_t)NCOL * 64;                 // 50000*64 fp8
    float* partsum = (float*)(ht_col1 + (size_t)NCOL * 64);         // 2*GGRID*64 fp32
    unsigned short* wt = (unsigned short*)(partsum + (size_t)2 * GGRID * 64); // 49152
    // CSR-build aliases (dead before gathers/prep): u16 partial (25.6 MB) + int bstart (25.6 MB)
    unsigned short* partial = (unsigned short*)agg_col;             // 16*HBLK*HB u16
    int* bstart = (int*)(partial + (size_t)16 * HBLK * HB);         // 8*HBLK*HB int

    float* r_out_rc = norms;
    float* r_in_rc  = norms + NROW;
    float* r_out_cr = norms + NROW + NCOL;
    float* r_in_cr  = norms + NROW + 2 * NCOL;

    unsigned short* wt0_rc = wt;
    unsigned short* wt0_cr = wt + 8192;
    unsigned short* wt1_rc = wt + 16384;
    unsigned short* wt1_cr = wt + 32768;

    // ---- CSR build (aliases live here) ----
    hist_lds<<<16 * HBLK, 512, 0, stream>>>(src_rc, dst_rc, src_cr, dst_cr, partial, E);
    reduce_norms2<<<512, 256, 0, stream>>>(partial, cnt, norms);
    scanA<<<200, 256, 0, stream>>>(cnt, bsum);
    scanB<<<1, 256, 0, stream>>>(bsum, cbase);
    scanC<<<200, 512, 0, stream>>>(cnt, cbase, ptr_rc, ptr_cr, E);
    block_starts<<<400, 256, 0, stream>>>(partial, bstart, ptr_rc, ptr_cr);
    csr_fill_sorted<<<8 * HBLK, 512, 0, stream>>>(
        src_rc, dst_rc, w_rc, r_out_rc, pair_rc,
        src_cr, dst_cr, w_cr, r_out_cr, pair_cr, bstart, E);

    // ---- fp8 feature tables + bf16 weights (aliases now dead) ----
    prep_tables<<<2048, 256, 0, stream>>>((const float4*)feat_row, (const float4*)feat_col,
                                          (unsigned*)f8_row, (unsigned*)f8_col, NROW * 64 / 4,
                                          W0_rc, W0_cr, W1_rc, W1_cr, wt);

    // ---- layer 1 ----
    gather64_2<<<2 * GGRID, 256, 0, stream>>>(f8_row, ptr_rc, pair_rc, agg_col,
                                              f8_col, ptr_cr, pair_cr, agg_row, NCOL);
    dense64_2<<<2 * DGRID, 256, 0, stream>>>(agg_col, r_in_rc, wt0_rc, b0_rc, h_col1,
                                             agg_row, r_in_cr, wt0_cr, b0_cr, h_row1, NCOL);

    // ---- layer 2: pre-transform h1@W1 -> split fp8 half-tables, then fused gather ----
    h1t_gemm2<<<2 * DGRID, 256, 0, stream>>>(h_row1, wt1_rc, ht_row0, ht_row1,
                                             h_col1, wt1_cr, ht_col0, ht_col1, NROW);
    hipMemsetAsync(out, 0, DH * sizeof(float), stream);
    gather_final<<<2 * GGRID, 256, 0, stream>>>(
        ht_row0, ht_row1, ptr_rc, pair_rc, r_in_rc, b1_rc,
        ht_col0, ht_col1, ptr_cr, pair_cr, r_in_cr, b1_cr,
        partsum, NCOL, 1.0f / NCOL);
    reduce_out2<<<64, 128, 0, stream>>>(partsum, out, 2 * GGRID);
}

// Round 17
// 296.919 us; speedup vs baseline: 1.1687x; 1.1323x over previous
//
#include <hip/hip_runtime.h>
#include <stdint.h>

constexpr int NROW = 50000;
constexpr int NCOL = 50000;
constexpr int DH   = 128;
constexpr int NTAB = 200000;   // [out_rc(NROW) | in_rc(NCOL) | out_cr(NCOL) | in_cr(NROW)]
constexpr int HB   = 12500;    // bins per section (quarter table), 50 KB LDS
constexpr int HBLK = 32;       // blocks per section (1024-thread blocks)
constexpr int DGRID = 1250;    // dense blocks per relation
constexpr int GGRID = 2048;    // gather blocks per relation
constexpr int CH    = 500;     // scan chunk size (100 chunks per table)

typedef __attribute__((ext_vector_type(8))) short short8;
typedef __attribute__((ext_vector_type(4))) float f32x4;
typedef __attribute__((ext_vector_type(2))) float f32x2;

__device__ __forceinline__ float bf_hi(unsigned u) { return __uint_as_float(u & 0xffff0000u); }
__device__ __forceinline__ unsigned short f2bf(float f) {   // RNE
    unsigned u = __float_as_uint(f);
    return (unsigned short)((u + 0x7fffu + ((u >> 16) & 1u)) >> 16);
}

// ---- fp8 OCP e4m3fn encode (RNE, clamp 448, subnormal-aware) ----
__device__ __forceinline__ unsigned char f2fp8(float f) {
    unsigned b = __float_as_uint(f);
    unsigned s = (b >> 24) & 0x80u;
    unsigned mag = b & 0x7fffffffu;
    if (mag >= 0x43e00000u) return (unsigned char)(s | 0x7eu);   // clamp to ±448
    unsigned r = mag + 0x7ffffu + ((mag >> 20) & 1u);
    int e = (int)(r >> 23) - 120;
    if (e < 1) {                                                  // subnormal: m * 2^-9
        float af = __uint_as_float(mag);
        unsigned m = (unsigned)(af * 512.f + 0.5f);
        if (m > 8u) m = 8u;
        return (unsigned char)(s | m);
    }
    return (unsigned char)(s | (unsigned)(e << 3) | ((r >> 20) & 7u));
}

// ---- fp8 x2 decode (HW cvt if available) ----
#if defined(__has_builtin) && __has_builtin(__builtin_amdgcn_cvt_pk_f32_fp8)
__device__ __forceinline__ f32x2 fp8x2f(unsigned v) {
    return __builtin_amdgcn_cvt_pk_f32_fp8((int)v, false);
}
#else
__device__ __forceinline__ float fp8_1(unsigned u) {
    unsigned s = (u & 0x80u) << 24, em = u & 0x7fu;
    if (em >= 8u) return __uint_as_float(s | ((em + 960u) << 20));
    float v = (float)em * 0.001953125f;
    return (u & 0x80u) ? -v : v;
}
__device__ __forceinline__ f32x2 fp8x2f(unsigned v) {
    f32x2 r; r.x = fp8_1(v & 0xffu); r.y = fp8_1((v >> 8) & 0xffu); return r;
}
#endif

// ---- degree histograms via LDS privatization; u16 partials; 1024-thread blocks ----
__global__ __launch_bounds__(1024) void hist_lds(
        const int* __restrict__ s_rc, const int* __restrict__ d_rc,
        const int* __restrict__ s_cr, const int* __restrict__ d_cr,
        unsigned short* __restrict__ partial, int E) {
    __shared__ int h[HB];
    const int sec = blockIdx.x >> 5;           // 0..15
    const int blk = blockIdx.x & (HBLK - 1);   // 0..31
    const int tab = sec >> 2;                  // 0..3 -> array
    const int lo  = (sec & 3) * HB;
    const int* __restrict__ arr = (tab == 0) ? s_rc : (tab == 1) ? d_rc
                                 : (tab == 2) ? s_cr : d_cr;
    for (int i = threadIdx.x; i < HB; i += blockDim.x) h[i] = 0;
    __syncthreads();
    const int stride = HBLK * blockDim.x;
    for (int i = blk * blockDim.x + threadIdx.x; i < E; i += stride) {
        int id = arr[i] - lo;
        if ((unsigned)id < (unsigned)HB) atomicAdd(&h[id], 1);   // LDS atomic
    }
    __syncthreads();
    unsigned short* __restrict__ out = partial + ((size_t)sec * HBLK + blk) * HB;
    for (int i = threadIdx.x; i < HB; i += blockDim.x) out[i] = (unsigned short)h[i];
}

// ---- reduce HBLK u16 partials/section -> cnt + norms ----
__global__ void reduce_norms2(const unsigned short* __restrict__ partial, int* __restrict__ cnt,
                              float* __restrict__ norms) {
    int stride = gridDim.x * blockDim.x;
    for (int i = blockIdx.x * blockDim.x + threadIdx.x; i < NTAB; i += stride) {
        int t = i / 50000;
        int r = i - t * 50000;
        int q = r / HB;
        int j = r - q * HB;
        const unsigned short* __restrict__ p = partial + ((size_t)(t * 4 + q) * HBLK) * HB + j;
        int s = 0;
#pragma unroll
        for (int b = 0; b < HBLK; ++b) s += p[(size_t)b * HB];
        cnt[i] = s;
        norms[i] = 1.0f / sqrtf((float)max(s, 1));
    }
}

// ---- parallel exclusive scan of the two dst-count tables, 3 phases ----
__global__ __launch_bounds__(256) void scanA(const int* __restrict__ cnt, int* __restrict__ bsum) {
    __shared__ int red[256];
    const int c = blockIdx.x;
    const int* __restrict__ cbl = cnt + ((c >= 100) ? 150000 : 50000);
    const int j0 = (c % 100) * CH;
    int s = 0;
    for (int i = threadIdx.x; i < CH; i += 256) s += cbl[j0 + i];
    red[threadIdx.x] = s;
    __syncthreads();
    for (int off = 128; off > 0; off >>= 1) {
        if (threadIdx.x < off) red[threadIdx.x] += red[threadIdx.x + off];
        __syncthreads();
    }
    if (threadIdx.x == 0) bsum[c] = red[0];
}

__global__ void scanB(const int* __restrict__ bsum, int* __restrict__ cbase) {
    __shared__ int b[200];
    for (int i = threadIdx.x; i < 200; i += blockDim.x) b[i] = bsum[i];
    __syncthreads();
    if (threadIdx.x < 2) {
        int run = 0;
        const int o = threadIdx.x * 100;
        for (int k = 0; k < 100; ++k) { cbase[o + k] = run; run += b[o + k]; }
    }
}

__global__ __launch_bounds__(512) void scanC(const int* __restrict__ cnt,
                                             const int* __restrict__ cbase,
                                             int* __restrict__ ptr_rc, int* __restrict__ ptr_cr,
                                             int E) {
    __shared__ int buf[512];
    const int c = blockIdx.x;
    const int table = (c >= 100);
    const int* __restrict__ cbl = cnt + (table ? 150000 : 50000);
    int* __restrict__ ptr = table ? ptr_cr : ptr_rc;
    const int j0 = (c % 100) * CH;
    const int t = threadIdx.x;
    const int v = (t < CH) ? cbl[j0 + t] : 0;
    buf[t] = v;
    __syncthreads();
    for (int off = 1; off < 512; off <<= 1) {
        int tmp = (t >= off) ? buf[t - off] : 0;
        __syncthreads();
        buf[t] += tmp;
        __syncthreads();
    }
    if (t < CH) ptr[j0 + t] = cbase[c] + buf[t] - v;
    if ((c % 100) == 99 && t == 0) ptr[50000] = E;
}

// ---- dst-section u16 partials -> absolute int block start positions ----
__global__ void block_starts(const unsigned short* __restrict__ partial, int* __restrict__ bstart,
                             const int* __restrict__ ptr_rc, const int* __restrict__ ptr_cr) {
    int stride = gridDim.x * blockDim.x;
    for (int i = blockIdx.x * blockDim.x + threadIdx.x; i < 8 * HB; i += stride) {
        int fsec = i / HB;                 // 0..7 = (rel, quarter)
        int j = i - fsec * HB;
        int rel = fsec >> 2, q = fsec & 3;
        int histsec = rel * 8 + 4 + q;     // dst tab = rel*2+1
        const int* __restrict__ ptr = rel ? ptr_cr : ptr_rc;
        int run = ptr[q * HB + j];
        const unsigned short* __restrict__ p = partial + ((size_t)histsec * HBLK) * HB + j;
        int* __restrict__ o = bstart + ((size_t)fsec * HBLK) * HB + j;
#pragma unroll
        for (int b = 0; b < HBLK; ++b) {
            o[(size_t)b * HB] = run;
            run += p[(size_t)b * HB];
        }
    }
}

// ---- CSR fill, XCD-affine (blockIdx%8 = section), 1024-thread blocks ----
__global__ __launch_bounds__(1024) void csr_fill_sorted(
        const int* __restrict__ sA, const int* __restrict__ dA,
        const float* __restrict__ wA, const float* __restrict__ routA, unsigned* __restrict__ pairA,
        const int* __restrict__ sB, const int* __restrict__ dB,
        const float* __restrict__ wB, const float* __restrict__ routB, unsigned* __restrict__ pairB,
        const int* __restrict__ bstart, int E) {
    __shared__ int offs[HB];
    const int fsec = blockIdx.x & 7;           // section -> XCD
    const int blk  = blockIdx.x >> 3;          // 0..31
    const int rel = fsec >> 2, q = fsec & 3;
    const int lo = q * HB;
    const int* __restrict__ src  = rel ? sB : sA;
    const int* __restrict__ dst  = rel ? dB : dA;
    const float* __restrict__ w  = rel ? wB : wA;
    const float* __restrict__ ro = rel ? routB : routA;
    unsigned* __restrict__ pair  = rel ? pairB : pairA;
    const int* __restrict__ bs = bstart + ((size_t)fsec * HBLK + blk) * HB;
    for (int i = threadIdx.x; i < HB; i += blockDim.x) offs[i] = bs[i];
    __syncthreads();
    const int stride = HBLK * blockDim.x;
    for (int i = blk * blockDim.x + threadIdx.x; i < E; i += stride) {
        int id = dst[i] - lo;
        if ((unsigned)id < (unsigned)HB) {
            int pos = atomicAdd(&offs[id], 1);            // LDS atomic
            int s = src[i];
            pair[pos] = (unsigned)s | ((unsigned)f2bf(w[i] * ro[s]) << 16);
        }
    }
}

// ---- fp32 -> fp8 feature tables + transposed bf16 weights, one launch ----
__global__ void prep_tables(const float4* __restrict__ fr, const float4* __restrict__ fc,
                            unsigned* __restrict__ f8r, unsigned* __restrict__ f8c, int nq,
                            const float* __restrict__ W0a, const float* __restrict__ W0b,
                            const float* __restrict__ W1a, const float* __restrict__ W1b,
                            unsigned short* __restrict__ wt) {
    const int total = 2 * nq + 49152;
    int stride = gridDim.x * blockDim.x;
    for (int i = blockIdx.x * blockDim.x + threadIdx.x; i < total; i += stride) {
        if (i < 2 * nq) {
            bool second = i >= nq;
            int k = second ? i - nq : i;
            float4 v = second ? fc[k] : fr[k];
            unsigned o = (unsigned)f2fp8(v.x) | ((unsigned)f2fp8(v.y) << 8)
                       | ((unsigned)f2fp8(v.z) << 16) | ((unsigned)f2fp8(v.w) << 24);
            if (second) f8c[k] = o; else f8r[k] = o;
        } else {
            int j = i - 2 * nq;
            const float* W; int K, base;
            if (j < 8192)       { W = W0a; K = 64;  base = 0; }
            else if (j < 16384) { W = W0b; K = 64;  base = 8192;  j -= 8192; }
            else if (j < 32768) { W = W1a; K = 128; base = 16384; j -= 16384; }
            else                { W = W1b; K = 128; base = 32768; j -= 32768; }
            int n = j / K, k = j - n * K;
            wt[base + n * K + k] = f2bf(W[k * DH + n]);
        }
    }
}

// ---- D=64 gather from fp8 tables, XCD-affine relation split, 8 edges/half in flight ----
__global__ void gather64_2(const uint8_t* __restrict__ hA, const int* __restrict__ ptrA,
                           const unsigned* __restrict__ pairA, unsigned short* __restrict__ aggA,
                           const uint8_t* __restrict__ hB, const int* __restrict__ ptrB,
                           const unsigned* __restrict__ pairB, unsigned short* __restrict__ aggB,
                           int n) {
    const int low  = blockIdx.x & 7;
    const int rel  = low >> 2;                  // XCDs 0-3: rel A, 4-7: rel B
    const int bid  = (blockIdx.x >> 3) * 4 + (low & 3);
    const uint8_t* __restrict__ h = rel ? hB : hA;
    const int* __restrict__ ptr  = rel ? ptrB : ptrA;
    const unsigned* __restrict__ pair = rel ? pairB : pairA;
    unsigned short* __restrict__ agg  = rel ? aggB : aggA;
    const int gw   = (bid * blockDim.x + threadIdx.x) >> 6;
    const int nw   = (GGRID * blockDim.x) >> 6;
    const int lane = threadIdx.x & 63;
    const int half = lane >> 5;
    const int c    = (lane & 31) << 1;          // column pair 0..62 (byte offset too)
    for (int node = gw; node < n; node += nw) {
        const int beg = ptr[node], end = ptr[node + 1];
        float ax[8], ay[8];
#pragma unroll
        for (int u = 0; u < 8; ++u) { ax[u] = 0.f; ay[u] = 0.f; }
        int j = beg + half;
        for (; j + 14 < end; j += 16) {         // 8 edges per half-wave in flight
            unsigned p[8], hv[8];
#pragma unroll
            for (int u = 0; u < 8; ++u) p[u] = pair[j + 2 * u];
#pragma unroll
            for (int u = 0; u < 8; ++u)
                hv[u] = *reinterpret_cast<const unsigned short*>(&h[((p[u] & 0xffffu) << 6) + c]);
#pragma unroll
            for (int u = 0; u < 8; ++u) {
                f32x2 d = fp8x2f(hv[u]);
                float w = bf_hi(p[u]);
                ax[u] = fmaf(d.x, w, ax[u]); ay[u] = fmaf(d.y, w, ay[u]);
            }
        }
        for (; j < end; j += 2) {
            unsigned p = pair[j];
            unsigned hv = *reinterpret_cast<const unsigned short*>(&h[((p & 0xffffu) << 6) + c]);
            f32x2 d = fp8x2f(hv);
            float w = bf_hi(p);
            ax[0] = fmaf(d.x, w, ax[0]); ay[0] = fmaf(d.y, w, ay[0]);
        }
        float ax_ = ((ax[0] + ax[1]) + (ax[2] + ax[3])) + ((ax[4] + ax[5]) + (ax[6] + ax[7]));
        float ay_ = ((ay[0] + ay[1]) + (ay[2] + ay[3])) + ((ay[4] + ay[5]) + (ay[6] + ay[7]));
        ax_ += __shfl_xor(ax_, 32);
        ay_ += __shfl_xor(ay_, 32);
        if (half == 0) {
            unsigned pk = (unsigned)f2bf(ax_) | ((unsigned)f2bf(ay_) << 16);
            *reinterpret_cast<unsigned*>(&agg[(size_t)node * 64 + c]) = pk;
        }
    }
}

// ---- layer-1 dense via MFMA 16x16x32 bf16, both relations fused ----
__global__ __launch_bounds__(256) void dense64_2(
        const unsigned short* __restrict__ aggA, const float* __restrict__ rinA,
        const unsigned short* __restrict__ wtA, const float* __restrict__ bA,
        unsigned short* __restrict__ outA,
        const unsigned short* __restrict__ aggB, const float* __restrict__ rinB,
        const unsigned short* __restrict__ wtB, const float* __restrict__ bB,
        unsigned short* __restrict__ outB, int n) {
    constexpr int K = 64, NCH = 2;
    const int rel = blockIdx.x >= DGRID;
    const int bid = rel ? blockIdx.x - DGRID : blockIdx.x;
    const unsigned short* __restrict__ agg = rel ? aggB : aggA;
    const float* __restrict__ rin = rel ? rinB : rinA;
    const unsigned short* __restrict__ wt = rel ? wtB : wtA;
    const float* __restrict__ b = rel ? bB : bA;
    unsigned short* __restrict__ outbf = rel ? outB : outA;

    const int wave = threadIdx.x >> 6;
    const int lane = threadIdx.x & 63;
    const int lrow = lane & 15;
    const int kgrp = lane >> 4;
    const int c0   = wave * 32;

    short8 bfr[2][NCH];
#pragma unroll
    for (int t = 0; t < 2; ++t)
#pragma unroll
        for (int ch = 0; ch < NCH; ++ch)
            bfr[t][ch] = *reinterpret_cast<const short8*>(
                &wt[(size_t)(c0 + t * 16 + lrow) * K + ch * 32 + kgrp * 8]);

    const float bias0 = b[c0 + lrow], bias1 = b[c0 + 16 + lrow];
    const int nstrip = n >> 4;
    for (int s = bid; s < nstrip; s += DGRID) {
        const int r0 = s << 4;
        f32x4 d0 = {0.f, 0.f, 0.f, 0.f}, d1 = {0.f, 0.f, 0.f, 0.f};
#pragma unroll
        for (int ch = 0; ch < NCH; ++ch) {
            short8 af = *reinterpret_cast<const short8*>(
                &agg[(size_t)(r0 + lrow) * K + ch * 32 + kgrp * 8]);
            d0 = __builtin_amdgcn_mfma_f32_16x16x32_bf16(af, bfr[0][ch], d0, 0, 0, 0);
            d1 = __builtin_amdgcn_mfma_f32_16x16x32_bf16(af, bfr[1][ch], d1, 0, 0, 0);
        }
#pragma unroll
        for (int i = 0; i < 4; ++i) {          // C/D: col=lane&15, row=(lane>>4)*4+i
            const int row = r0 + kgrp * 4 + i;
            const float rv = rin[row];
            outbf[(size_t)row * DH + c0 + lrow]      = f2bf(fmaxf(fmaf(rv, d0[i], bias0), 0.f));
            outbf[(size_t)row * DH + c0 + 16 + lrow] = f2bf(fmaxf(fmaf(rv, d1[i], bias1), 0.f));
        }
    }
}

// ---- h1t = h1 @ W1 -> fp8 tables (pre-transform; both relations fused) ----
__global__ __launch_bounds__(256) void h1t_gemm2(
        const unsigned short* __restrict__ hA, const unsigned short* __restrict__ wtA,
        uint8_t* __restrict__ htA,
        const unsigned short* __restrict__ hB, const unsigned short* __restrict__ wtB,
        uint8_t* __restrict__ htB, int n) {
    constexpr int K = 128, NCH = 4;
    const int rel = blockIdx.x >= DGRID;
    const int bid = rel ? blockIdx.x - DGRID : blockIdx.x;
    const unsigned short* __restrict__ h = rel ? hB : hA;
    const unsigned short* __restrict__ wt = rel ? wtB : wtA;
    uint8_t* __restrict__ ht = rel ? htB : htA;

    const int wave = threadIdx.x >> 6;
    const int lane = threadIdx.x & 63;
    const int lrow = lane & 15;
    const int kgrp = lane >> 4;
    const int c0   = wave * 32;

    short8 bfr[2][NCH];
#pragma unroll
    for (int t = 0; t < 2; ++t)
#pragma unroll
        for (int ch = 0; ch < NCH; ++ch)
            bfr[t][ch] = *reinterpret_cast<const short8*>(
                &wt[(size_t)(c0 + t * 16 + lrow) * K + ch * 32 + kgrp * 8]);

    const int nstrip = n >> 4;
    for (int s = bid; s < nstrip; s += DGRID) {
        const int r0 = s << 4;
        f32x4 d0 = {0.f, 0.f, 0.f, 0.f}, d1 = {0.f, 0.f, 0.f, 0.f};
#pragma unroll
        for (int ch = 0; ch < NCH; ++ch) {
            short8 af = *reinterpret_cast<const short8*>(
                &h[(size_t)(r0 + lrow) * K + ch * 32 + kgrp * 8]);
            d0 = __builtin_amdgcn_mfma_f32_16x16x32_bf16(af, bfr[0][ch], d0, 0, 0, 0);
            d1 = __builtin_amdgcn_mfma_f32_16x16x32_bf16(af, bfr[1][ch], d1, 0, 0, 0);
        }
#pragma unroll
        for (int i = 0; i < 4; ++i) {
            const int row = r0 + kgrp * 4 + i;
            ht[(size_t)row * DH + c0 + lrow]      = f2fp8(d0[i]);
            ht[(size_t)row * DH + c0 + 16 + lrow] = f2fp8(d1[i]);
        }
    }
}

// ---- final gather: 8 edges in flight, combined 128B ht rows, fused relu+mean ----
__global__ __launch_bounds__(256) void gather_final(
        const uint8_t* __restrict__ htA, const int* __restrict__ ptrA,
        const unsigned* __restrict__ pairA, const float* __restrict__ rinA,
        const float* __restrict__ bA,
        const uint8_t* __restrict__ htB, const int* __restrict__ ptrB,
        const unsigned* __restrict__ pairB, const float* __restrict__ rinB,
        const float* __restrict__ bB,
        float* __restrict__ partsum, int n, float invn) {
    const int low  = blockIdx.x & 7;
    const int rel  = low >> 2;                  // XCDs 0-3: rel A, 4-7: rel B
    const int bid  = (blockIdx.x >> 3) * 4 + (low & 3);
    const uint8_t* __restrict__ ht = rel ? htB : htA;
    const int* __restrict__ ptr  = rel ? ptrB : ptrA;
    const unsigned* __restrict__ pair = rel ? pairB : pairA;
    const float* __restrict__ rin = rel ? rinB : rinA;
    const float* __restrict__ b   = rel ? bB : bA;

    const int gw   = (bid * blockDim.x + threadIdx.x) >> 6;
    const int nw   = (GGRID * blockDim.x) >> 6;
    const int lane = threadIdx.x & 63;
    const int c    = lane << 1;                 // cols c, c+1 (byte offsets too)
    const float bias0 = b[c], bias1 = b[c + 1];
    float m0 = 0.f, m1 = 0.f;

    for (int node = gw; node < n; node += nw) {
        const int beg = ptr[node], end = ptr[node + 1];
        float ax[8], ay[8];
#pragma unroll
        for (int u = 0; u < 8; ++u) { ax[u] = 0.f; ay[u] = 0.f; }
        int j = beg;
        for (; j + 7 < end; j += 8) {           // 8 edges in flight
            unsigned p[8]; unsigned hv[8];
#pragma unroll
            for (int u = 0; u < 8; ++u) p[u] = pair[j + u];
#pragma unroll
            for (int u = 0; u < 8; ++u)
                hv[u] = *reinterpret_cast<const unsigned short*>(&ht[((size_t)(p[u] & 0xffffu) << 7) + c]);
#pragma unroll
            for (int u = 0; u < 8; ++u) {
                f32x2 d = fp8x2f(hv[u]);
                float w = bf_hi(p[u]);
                ax[u] = fmaf(d.x, w, ax[u]);
                ay[u] = fmaf(d.y, w, ay[u]);
            }
        }
        for (; j < end; ++j) {
            unsigned p = pair[j];
            unsigned hv = *reinterpret_cast<const unsigned short*>(&ht[((size_t)(p & 0xffffu) << 7) + c]);
            f32x2 d = fp8x2f(hv);
            float w = bf_hi(p);
            ax[0] = fmaf(d.x, w, ax[0]); ay[0] = fmaf(d.y, w, ay[0]);
        }
        float accx = ((ax[0] + ax[1]) + (ax[2] + ax[3])) + ((ax[4] + ax[5]) + (ax[6] + ax[7]));
        float accy = ((ay[0] + ay[1]) + (ay[2] + ay[3])) + ((ay[4] + ay[5]) + (ay[6] + ay[7]));
        const float rv = rin[node];
        m0 += fmaxf(fmaf(rv, accx, bias0), 0.f);
        m1 += fmaxf(fmaf(rv, accy, bias1), 0.f);
    }

    __shared__ float red[512];
    red[threadIdx.x] = m0;
    red[256 + threadIdx.x] = m1;
    __syncthreads();
    if (threadIdx.x < 64) {
        float s0 = red[threadIdx.x] + red[threadIdx.x + 64] + red[threadIdx.x + 128] + red[threadIdx.x + 192];
        float s1 = red[256 + threadIdx.x] + red[256 + threadIdx.x + 64]
                 + red[256 + threadIdx.x + 128] + red[256 + threadIdx.x + 192];
        float* part = partsum + (size_t)blockIdx.x * DH;
        part[2 * threadIdx.x]     = s0 * invn;
        part[2 * threadIdx.x + 1] = s1 * invn;
    }
}

// ---- sum partial rows into out[0..127] ----
__global__ void reduce_out(const float* __restrict__ partial, float* __restrict__ out, int nrows) {
    const int t = threadIdx.x;                 // 128
    const int per = nrows / gridDim.x;
    const int b0 = blockIdx.x * per;
    float s = 0.f;
    for (int b = b0; b < b0 + per; ++b) s += partial[(size_t)b * DH + t];
    atomicAdd(&out[t], s);
}

extern "C" void kernel_launch(void* const* d_in, const int* in_sizes, int n_in,
                              void* d_out, int out_size, void* d_ws, size_t ws_size,
                              hipStream_t stream) {
    const float* feat_row = (const float*)d_in[0];
    const float* feat_col = (const float*)d_in[1];
    const int*   src_rc   = (const int*)d_in[2];
    const int*   dst_rc   = (const int*)d_in[3];
    const float* w_rc     = (const float*)d_in[4];
    const int*   src_cr   = (const int*)d_in[5];
    const int*   dst_cr   = (const int*)d_in[6];
    const float* w_cr     = (const float*)d_in[7];
    const float* W0_rc    = (const float*)d_in[8];
    const float* b0_rc    = (const float*)d_in[9];
    const float* W0_cr    = (const float*)d_in[10];
    const float* b0_cr    = (const float*)d_in[11];
    const float* W1_rc    = (const float*)d_in[12];
    const float* b1_rc    = (const float*)d_in[13];
    const float* W1_cr    = (const float*)d_in[14];
    const float* b1_cr    = (const float*)d_in[15];
    const int E = in_sizes[2];
    float* out = (float*)d_out;

    // ---- workspace layout (~75 MB) ----
    int*   cnt     = (int*)d_ws;                        // 200000
    float* norms   = (float*)(cnt + 200000);            // 200000
    int*   ptr_rc  = (int*)(norms + 200000);            // 50004
    int*   ptr_cr  = ptr_rc + 50004;                    // 50004
    int*   bsum    = ptr_cr + 50004;                    // 200
    int*   cbase   = bsum + 200;                        // 216 (pad)
    unsigned* pair_rc = (unsigned*)(cbase + 216);       // E
    unsigned* pair_cr = pair_rc + E;                    // E
    unsigned short* agg_col = (unsigned short*)(pair_cr + E);       // 50000*64 bf16
    unsigned short* agg_row = agg_col + (size_t)NCOL * 64;          // 50000*64 bf16
    uint8_t* f8_row = (uint8_t*)(agg_row + (size_t)NROW * 64);      // 50000*64 fp8
    uint8_t* f8_col = f8_row + (size_t)NROW * 64;                   // 50000*64 fp8
    unsigned short* h_col1 = (unsigned short*)(f8_col + (size_t)NCOL * 64); // 50000*128 bf16
    unsigned short* h_row1 = h_col1 + (size_t)NCOL * DH;                    // 50000*128 bf16
    uint8_t* ht_row = (uint8_t*)(h_row1 + (size_t)NROW * DH);       // 50000*128 fp8
    uint8_t* ht_col = ht_row + (size_t)NROW * DH;                   // 50000*128 fp8
    float* partsum = (float*)(ht_col + (size_t)NCOL * DH);          // 2*GGRID*128 fp32
    unsigned short* wt = (unsigned short*)(partsum + (size_t)2 * GGRID * DH); // 49152
    // CSR-build aliases (dead before gathers/prep): u16 partial (12.8 MB) + int bstart (12.8 MB)
    unsigned short* partial = (unsigned short*)agg_col;             // 16*HBLK*HB u16
    int* bstart = (int*)(partial + (size_t)16 * HBLK * HB);         // 8*HBLK*HB int

    float* r_out_rc = norms;
    float* r_in_rc  = norms + NROW;
    float* r_out_cr = norms + NROW + NCOL;
    float* r_in_cr  = norms + NROW + 2 * NCOL;

    unsigned short* wt0_rc = wt;
    unsigned short* wt0_cr = wt + 8192;
    unsigned short* wt1_rc = wt + 16384;
    unsigned short* wt1_cr = wt + 32768;

    // ---- CSR build (aliases live here) ----
    hist_lds<<<16 * HBLK, 1024, 0, stream>>>(src_rc, dst_rc, src_cr, dst_cr, partial, E);
    reduce_norms2<<<512, 256, 0, stream>>>(partial, cnt, norms);
    scanA<<<200, 256, 0, stream>>>(cnt, bsum);
    scanB<<<1, 256, 0, stream>>>(bsum, cbase);
    scanC<<<200, 512, 0, stream>>>(cnt, cbase, ptr_rc, ptr_cr, E);
    block_starts<<<400, 256, 0, stream>>>(partial, bstart, ptr_rc, ptr_cr);
    csr_fill_sorted<<<8 * HBLK, 1024, 0, stream>>>(
        src_rc, dst_rc, w_rc, r_out_rc, pair_rc,
        src_cr, dst_cr, w_cr, r_out_cr, pair_cr, bstart, E);

    // ---- fp8 feature tables + bf16 weights (aliases now dead) ----
    prep_tables<<<2048, 256, 0, stream>>>((const float4*)feat_row, (const float4*)feat_col,
                                          (unsigned*)f8_row, (unsigned*)f8_col, NROW * 64 / 4,
                                          W0_rc, W0_cr, W1_rc, W1_cr, wt);

    // ---- layer 1 ----
    gather64_2<<<2 * GGRID, 256, 0, stream>>>(f8_row, ptr_rc, pair_rc, agg_col,
                                              f8_col, ptr_cr, pair_cr, agg_row, NCOL);
    dense64_2<<<2 * DGRID, 256, 0, stream>>>(agg_col, r_in_rc, wt0_rc, b0_rc, h_col1,
                                             agg_row, r_in_cr, wt0_cr, b0_cr, h_row1, NCOL);

    // ---- layer 2: pre-transform h1@W1 -> fp8, then fused gather+relu+mean ----
    h1t_gemm2<<<2 * DGRID, 256, 0, stream>>>(h_row1, wt1_rc, ht_row,
                                             h_col1, wt1_cr, ht_col, NROW);
    hipMemsetAsync(out, 0, DH * sizeof(float), stream);
    gather_final<<<2 * GGRID, 256, 0, stream>>>(
        ht_row, ptr_rc, pair_rc, r_in_rc, b1_rc,
        ht_col, ptr_cr, pair_cr, r_in_cr, b1_cr,
        partsum, NCOL, 1.0f / NCOL);
    reduce_out<<<32, 128, 0, stream>>>(partsum, out, 2 * GGRID);
}

// Round 18
// 285.555 us; speedup vs baseline: 1.2152x; 1.0398x over previous
//
#include <hip/hip_runtime.h>
#include <stdint.h>

constexpr int NROW = 50000;
constexpr int NCOL = 50000;
constexpr int DH   = 128;
constexpr int NTAB = 200000;   // [out_rc(NROW) | in_rc(NCOL) | out_cr(NCOL) | in_cr(NROW)]
constexpr int HB   = 12500;    // bins per section (quarter table), 50 KB LDS
constexpr int HBLK = 32;       // blocks per section (1024-thread blocks)
constexpr int DGRID = 1250;    // dense blocks per relation
constexpr int GGRID = 2048;    // gather blocks per relation
constexpr int CH    = 500;     // scan chunk size (100 chunks per table)

typedef __attribute__((ext_vector_type(8))) short short8;
typedef __attribute__((ext_vector_type(4))) float f32x4;
typedef __attribute__((ext_vector_type(2))) float f32x2;

__device__ __forceinline__ float bf_hi(unsigned u) { return __uint_as_float(u & 0xffff0000u); }
__device__ __forceinline__ unsigned short f2bf(float f) {   // RNE
    unsigned u = __float_as_uint(f);
    return (unsigned short)((u + 0x7fffu + ((u >> 16) & 1u)) >> 16);
}

// ---- fp8 OCP e4m3fn encode (RNE, clamp 448, subnormal-aware) ----
__device__ __forceinline__ unsigned char f2fp8(float f) {
    unsigned b = __float_as_uint(f);
    unsigned s = (b >> 24) & 0x80u;
    unsigned mag = b & 0x7fffffffu;
    if (mag >= 0x43e00000u) return (unsigned char)(s | 0x7eu);   // clamp to ±448
    unsigned r = mag + 0x7ffffu + ((mag >> 20) & 1u);
    int e = (int)(r >> 23) - 120;
    if (e < 1) {                                                  // subnormal: m * 2^-9
        float af = __uint_as_float(mag);
        unsigned m = (unsigned)(af * 512.f + 0.5f);
        if (m > 8u) m = 8u;
        return (unsigned char)(s | m);
    }
    return (unsigned char)(s | (unsigned)(e << 3) | ((r >> 20) & 7u));
}

// ---- fp8 decode helpers (HW cvt if available) ----
#if defined(__has_builtin) && __has_builtin(__builtin_amdgcn_cvt_pk_f32_fp8)
__device__ __forceinline__ f32x2 fp8x2f(unsigned v) {
    return __builtin_amdgcn_cvt_pk_f32_fp8((int)v, false);
}
__device__ __forceinline__ f32x4 fp8x4f(unsigned v) {
    f32x2 lo = __builtin_amdgcn_cvt_pk_f32_fp8((int)v, false);
    f32x2 hi = __builtin_amdgcn_cvt_pk_f32_fp8((int)v, true);
    f32x4 r; r.x = lo.x; r.y = lo.y; r.z = hi.x; r.w = hi.y; return r;
}
#else
__device__ __forceinline__ float fp8_1(unsigned u) {
    unsigned s = (u & 0x80u) << 24, em = u & 0x7fu;
    if (em >= 8u) return __uint_as_float(s | ((em + 960u) << 20));
    float v = (float)em * 0.001953125f;
    return (u & 0x80u) ? -v : v;
}
__device__ __forceinline__ f32x2 fp8x2f(unsigned v) {
    f32x2 r; r.x = fp8_1(v & 0xffu); r.y = fp8_1((v >> 8) & 0xffu); return r;
}
__device__ __forceinline__ f32x4 fp8x4f(unsigned v) {
    f32x4 r; r.x = fp8_1(v & 0xffu); r.y = fp8_1((v >> 8) & 0xffu);
    r.z = fp8_1((v >> 16) & 0xffu); r.w = fp8_1((v >> 24) & 0xffu); return r;
}
#endif

// ---- degree histograms via LDS privatization; u16 partials; 1024-thread blocks ----
__global__ __launch_bounds__(1024) void hist_lds(
        const int* __restrict__ s_rc, const int* __restrict__ d_rc,
        const int* __restrict__ s_cr, const int* __restrict__ d_cr,
        unsigned short* __restrict__ partial, int E) {
    __shared__ int h[HB];
    const int sec = blockIdx.x >> 5;           // 0..15
    const int blk = blockIdx.x & (HBLK - 1);   // 0..31
    const int tab = sec >> 2;                  // 0..3 -> array
    const int lo  = (sec & 3) * HB;
    const int* __restrict__ arr = (tab == 0) ? s_rc : (tab == 1) ? d_rc
                                 : (tab == 2) ? s_cr : d_cr;
    for (int i = threadIdx.x; i < HB; i += blockDim.x) h[i] = 0;
    __syncthreads();
    const int stride = HBLK * blockDim.x;
    for (int i = blk * blockDim.x + threadIdx.x; i < E; i += stride) {
        int id = arr[i] - lo;
        if ((unsigned)id < (unsigned)HB) atomicAdd(&h[id], 1);   // LDS atomic
    }
    __syncthreads();
    unsigned short* __restrict__ out = partial + ((size_t)sec * HBLK + blk) * HB;
    for (int i = threadIdx.x; i < HB; i += blockDim.x) out[i] = (unsigned short)h[i];
}

// ---- reduce HBLK u16 partials/section -> cnt + norms ----
__global__ void reduce_norms2(const unsigned short* __restrict__ partial, int* __restrict__ cnt,
                              float* __restrict__ norms) {
    int stride = gridDim.x * blockDim.x;
    for (int i = blockIdx.x * blockDim.x + threadIdx.x; i < NTAB; i += stride) {
        int t = i / 50000;
        int r = i - t * 50000;
        int q = r / HB;
        int j = r - q * HB;
        const unsigned short* __restrict__ p = partial + ((size_t)(t * 4 + q) * HBLK) * HB + j;
        int s = 0;
#pragma unroll
        for (int b = 0; b < HBLK; ++b) s += p[(size_t)b * HB];
        cnt[i] = s;
        norms[i] = 1.0f / sqrtf((float)max(s, 1));
    }
}

// ---- parallel exclusive scan of the two dst-count tables, 3 phases ----
__global__ __launch_bounds__(256) void scanA(const int* __restrict__ cnt, int* __restrict__ bsum) {
    __shared__ int red[256];
    const int c = blockIdx.x;
    const int* __restrict__ cbl = cnt + ((c >= 100) ? 150000 : 50000);
    const int j0 = (c % 100) * CH;
    int s = 0;
    for (int i = threadIdx.x; i < CH; i += 256) s += cbl[j0 + i];
    red[threadIdx.x] = s;
    __syncthreads();
    for (int off = 128; off > 0; off >>= 1) {
        if (threadIdx.x < off) red[threadIdx.x] += red[threadIdx.x + off];
        __syncthreads();
    }
    if (threadIdx.x == 0) bsum[c] = red[0];
}

__global__ void scanB(const int* __restrict__ bsum, int* __restrict__ cbase) {
    __shared__ int b[200];
    for (int i = threadIdx.x; i < 200; i += blockDim.x) b[i] = bsum[i];
    __syncthreads();
    if (threadIdx.x < 2) {
        int run = 0;
        const int o = threadIdx.x * 100;
        for (int k = 0; k < 100; ++k) { cbase[o + k] = run; run += b[o + k]; }
    }
}

__global__ __launch_bounds__(512) void scanC(const int* __restrict__ cnt,
                                             const int* __restrict__ cbase,
                                             int* __restrict__ ptr_rc, int* __restrict__ ptr_cr,
                                             int E) {
    __shared__ int buf[512];
    const int c = blockIdx.x;
    const int table = (c >= 100);
    const int* __restrict__ cbl = cnt + (table ? 150000 : 50000);
    int* __restrict__ ptr = table ? ptr_cr : ptr_rc;
    const int j0 = (c % 100) * CH;
    const int t = threadIdx.x;
    const int v = (t < CH) ? cbl[j0 + t] : 0;
    buf[t] = v;
    __syncthreads();
    for (int off = 1; off < 512; off <<= 1) {
        int tmp = (t >= off) ? buf[t - off] : 0;
        __syncthreads();
        buf[t] += tmp;
        __syncthreads();
    }
    if (t < CH) ptr[j0 + t] = cbase[c] + buf[t] - v;
    if ((c % 100) == 99 && t == 0) ptr[50000] = E;
}

// ---- dst-section u16 partials -> absolute int block start positions ----
__global__ void block_starts(const unsigned short* __restrict__ partial, int* __restrict__ bstart,
                             const int* __restrict__ ptr_rc, const int* __restrict__ ptr_cr) {
    int stride = gridDim.x * blockDim.x;
    for (int i = blockIdx.x * blockDim.x + threadIdx.x; i < 8 * HB; i += stride) {
        int fsec = i / HB;                 // 0..7 = (rel, quarter)
        int j = i - fsec * HB;
        int rel = fsec >> 2, q = fsec & 3;
        int histsec = rel * 8 + 4 + q;     // dst tab = rel*2+1
        const int* __restrict__ ptr = rel ? ptr_cr : ptr_rc;
        int run = ptr[q * HB + j];
        const unsigned short* __restrict__ p = partial + ((size_t)histsec * HBLK) * HB + j;
        int* __restrict__ o = bstart + ((size_t)fsec * HBLK) * HB + j;
#pragma unroll
        for (int b = 0; b < HBLK; ++b) {
            o[(size_t)b * HB] = run;
            run += p[(size_t)b * HB];
        }
    }
}

// ---- CSR fill, XCD-affine (blockIdx%8 = section), 1024-thread blocks ----
__global__ __launch_bounds__(1024) void csr_fill_sorted(
        const int* __restrict__ sA, const int* __restrict__ dA,
        const float* __restrict__ wA, const float* __restrict__ routA, unsigned* __restrict__ pairA,
        const int* __restrict__ sB, const int* __restrict__ dB,
        const float* __restrict__ wB, const float* __restrict__ routB, unsigned* __restrict__ pairB,
        const int* __restrict__ bstart, int E) {
    __shared__ int offs[HB];
    const int fsec = blockIdx.x & 7;           // section -> XCD
    const int blk  = blockIdx.x >> 3;          // 0..31
    const int rel = fsec >> 2, q = fsec & 3;
    const int lo = q * HB;
    const int* __restrict__ src  = rel ? sB : sA;
    const int* __restrict__ dst  = rel ? dB : dA;
    const float* __restrict__ w  = rel ? wB : wA;
    const float* __restrict__ ro = rel ? routB : routA;
    unsigned* __restrict__ pair  = rel ? pairB : pairA;
    const int* __restrict__ bs = bstart + ((size_t)fsec * HBLK + blk) * HB;
    for (int i = threadIdx.x; i < HB; i += blockDim.x) offs[i] = bs[i];
    __syncthreads();
    const int stride = HBLK * blockDim.x;
    for (int i = blk * blockDim.x + threadIdx.x; i < E; i += stride) {
        int id = dst[i] - lo;
        if ((unsigned)id < (unsigned)HB) {
            int pos = atomicAdd(&offs[id], 1);            // LDS atomic
            int s = src[i];
            pair[pos] = (unsigned)s | ((unsigned)f2bf(w[i] * ro[s]) << 16);
        }
    }
}

// ---- fp32 -> fp8 feature tables + transposed bf16 weights, one launch ----
__global__ void prep_tables(const float4* __restrict__ fr, const float4* __restrict__ fc,
                            unsigned* __restrict__ f8r, unsigned* __restrict__ f8c, int nq,
                            const float* __restrict__ W0a, const float* __restrict__ W0b,
                            const float* __restrict__ W1a, const float* __restrict__ W1b,
                            unsigned short* __restrict__ wt) {
    const int total = 2 * nq + 49152;
    int stride = gridDim.x * blockDim.x;
    for (int i = blockIdx.x * blockDim.x + threadIdx.x; i < total; i += stride) {
        if (i < 2 * nq) {
            bool second = i >= nq;
            int k = second ? i - nq : i;
            float4 v = second ? fc[k] : fr[k];
            unsigned o = (unsigned)f2fp8(v.x) | ((unsigned)f2fp8(v.y) << 8)
                       | ((unsigned)f2fp8(v.z) << 16) | ((unsigned)f2fp8(v.w) << 24);
            if (second) f8c[k] = o; else f8r[k] = o;
        } else {
            int j = i - 2 * nq;
            const float* W; int K, base;
            if (j < 8192)       { W = W0a; K = 64;  base = 0; }
            else if (j < 16384) { W = W0b; K = 64;  base = 8192;  j -= 8192; }
            else if (j < 32768) { W = W1a; K = 128; base = 16384; j -= 16384; }
            else                { W = W1b; K = 128; base = 32768; j -= 32768; }
            int n = j / K, k = j - n * K;
            wt[base + n * K + k] = f2bf(W[k * DH + n]);
        }
    }
}

// ---- D=64 gather from fp8 tables, XCD-affine relation split, 8 edges/half in flight ----
__global__ void gather64_2(const uint8_t* __restrict__ hA, const int* __restrict__ ptrA,
                           const unsigned* __restrict__ pairA, unsigned short* __restrict__ aggA,
                           const uint8_t* __restrict__ hB, const int* __restrict__ ptrB,
                           const unsigned* __restrict__ pairB, unsigned short* __restrict__ aggB,
                           int n) {
    const int low  = blockIdx.x & 7;
    const int rel  = low >> 2;                  // XCDs 0-3: rel A, 4-7: rel B
    const int bid  = (blockIdx.x >> 3) * 4 + (low & 3);
    const uint8_t* __restrict__ h = rel ? hB : hA;
    const int* __restrict__ ptr  = rel ? ptrB : ptrA;
    const unsigned* __restrict__ pair = rel ? pairB : pairA;
    unsigned short* __restrict__ agg  = rel ? aggB : aggA;
    const int gw   = (bid * blockDim.x + threadIdx.x) >> 6;
    const int nw   = (GGRID * blockDim.x) >> 6;
    const int lane = threadIdx.x & 63;
    const int half = lane >> 5;
    const int c    = (lane & 31) << 1;          // column pair 0..62 (byte offset too)
    for (int node = gw; node < n; node += nw) {
        const int beg = ptr[node], end = ptr[node + 1];
        float ax[8], ay[8];
#pragma unroll
        for (int u = 0; u < 8; ++u) { ax[u] = 0.f; ay[u] = 0.f; }
        int j = beg + half;
        for (; j + 14 < end; j += 16) {         // 8 edges per half-wave in flight
            unsigned p[8], hv[8];
#pragma unroll
            for (int u = 0; u < 8; ++u) p[u] = pair[j + 2 * u];
#pragma unroll
            for (int u = 0; u < 8; ++u)
                hv[u] = *reinterpret_cast<const unsigned short*>(&h[((p[u] & 0xffffu) << 6) + c]);
#pragma unroll
            for (int u = 0; u < 8; ++u) {
                f32x2 d = fp8x2f(hv[u]);
                float w = bf_hi(p[u]);
                ax[u] = fmaf(d.x, w, ax[u]); ay[u] = fmaf(d.y, w, ay[u]);
            }
        }
        for (; j < end; j += 2) {
            unsigned p = pair[j];
            unsigned hv = *reinterpret_cast<const unsigned short*>(&h[((p & 0xffffu) << 6) + c]);
            f32x2 d = fp8x2f(hv);
            float w = bf_hi(p);
            ax[0] = fmaf(d.x, w, ax[0]); ay[0] = fmaf(d.y, w, ay[0]);
        }
        float ax_ = ((ax[0] + ax[1]) + (ax[2] + ax[3])) + ((ax[4] + ax[5]) + (ax[6] + ax[7]));
        float ay_ = ((ay[0] + ay[1]) + (ay[2] + ay[3])) + ((ay[4] + ay[5]) + (ay[6] + ay[7]));
        ax_ += __shfl_xor(ax_, 32);
        ay_ += __shfl_xor(ay_, 32);
        if (half == 0) {
            unsigned pk = (unsigned)f2bf(ax_) | ((unsigned)f2bf(ay_) << 16);
            *reinterpret_cast<unsigned*>(&agg[(size_t)node * 64 + c]) = pk;
        }
    }
}

// ---- layer-1 dense via MFMA 16x16x32 bf16, both relations fused ----
__global__ __launch_bounds__(256) void dense64_2(
        const unsigned short* __restrict__ aggA, const float* __restrict__ rinA,
        const unsigned short* __restrict__ wtA, const float* __restrict__ bA,
        unsigned short* __restrict__ outA,
        const unsigned short* __restrict__ aggB, const float* __restrict__ rinB,
        const unsigned short* __restrict__ wtB, const float* __restrict__ bB,
        unsigned short* __restrict__ outB, int n) {
    constexpr int K = 64, NCH = 2;
    const int rel = blockIdx.x >= DGRID;
    const int bid = rel ? blockIdx.x - DGRID : blockIdx.x;
    const unsigned short* __restrict__ agg = rel ? aggB : aggA;
    const float* __restrict__ rin = rel ? rinB : rinA;
    const unsigned short* __restrict__ wt = rel ? wtB : wtA;
    const float* __restrict__ b = rel ? bB : bA;
    unsigned short* __restrict__ outbf = rel ? outB : outA;

    const int wave = threadIdx.x >> 6;
    const int lane = threadIdx.x & 63;
    const int lrow = lane & 15;
    const int kgrp = lane >> 4;
    const int c0   = wave * 32;

    short8 bfr[2][NCH];
#pragma unroll
    for (int t = 0; t < 2; ++t)
#pragma unroll
        for (int ch = 0; ch < NCH; ++ch)
            bfr[t][ch] = *reinterpret_cast<const short8*>(
                &wt[(size_t)(c0 + t * 16 + lrow) * K + ch * 32 + kgrp * 8]);

    const float bias0 = b[c0 + lrow], bias1 = b[c0 + 16 + lrow];
    const int nstrip = n >> 4;
    for (int s = bid; s < nstrip; s += DGRID) {
        const int r0 = s << 4;
        f32x4 d0 = {0.f, 0.f, 0.f, 0.f}, d1 = {0.f, 0.f, 0.f, 0.f};
#pragma unroll
        for (int ch = 0; ch < NCH; ++ch) {
            short8 af = *reinterpret_cast<const short8*>(
                &agg[(size_t)(r0 + lrow) * K + ch * 32 + kgrp * 8]);
            d0 = __builtin_amdgcn_mfma_f32_16x16x32_bf16(af, bfr[0][ch], d0, 0, 0, 0);
            d1 = __builtin_amdgcn_mfma_f32_16x16x32_bf16(af, bfr[1][ch], d1, 0, 0, 0);
        }
#pragma unroll
        for (int i = 0; i < 4; ++i) {          // C/D: col=lane&15, row=(lane>>4)*4+i
            const int row = r0 + kgrp * 4 + i;
            const float rv = rin[row];
            outbf[(size_t)row * DH + c0 + lrow]      = f2bf(fmaxf(fmaf(rv, d0[i], bias0), 0.f));
            outbf[(size_t)row * DH + c0 + 16 + lrow] = f2bf(fmaxf(fmaf(rv, d1[i], bias1), 0.f));
        }
    }
}

// ---- h1t = h1 @ W1 -> fp8 tables (pre-transform; both relations fused) ----
__global__ __launch_bounds__(256) void h1t_gemm2(
        const unsigned short* __restrict__ hA, const unsigned short* __restrict__ wtA,
        uint8_t* __restrict__ htA,
        const unsigned short* __restrict__ hB, const unsigned short* __restrict__ wtB,
        uint8_t* __restrict__ htB, int n) {
    constexpr int K = 128, NCH = 4;
    const int rel = blockIdx.x >= DGRID;
    const int bid = rel ? blockIdx.x - DGRID : blockIdx.x;
    const unsigned short* __restrict__ h = rel ? hB : hA;
    const unsigned short* __restrict__ wt = rel ? wtB : wtA;
    uint8_t* __restrict__ ht = rel ? htB : htA;

    const int wave = threadIdx.x >> 6;
    const int lane = threadIdx.x & 63;
    const int lrow = lane & 15;
    const int kgrp = lane >> 4;
    const int c0   = wave * 32;

    short8 bfr[2][NCH];
#pragma unroll
    for (int t = 0; t < 2; ++t)
#pragma unroll
        for (int ch = 0; ch < NCH; ++ch)
            bfr[t][ch] = *reinterpret_cast<const short8*>(
                &wt[(size_t)(c0 + t * 16 + lrow) * K + ch * 32 + kgrp * 8]);

    const int nstrip = n >> 4;
    for (int s = bid; s < nstrip; s += DGRID) {
        const int r0 = s << 4;
        f32x4 d0 = {0.f, 0.f, 0.f, 0.f}, d1 = {0.f, 0.f, 0.f, 0.f};
#pragma unroll
        for (int ch = 0; ch < NCH; ++ch) {
            short8 af = *reinterpret_cast<const short8*>(
                &h[(size_t)(r0 + lrow) * K + ch * 32 + kgrp * 8]);
            d0 = __builtin_amdgcn_mfma_f32_16x16x32_bf16(af, bfr[0][ch], d0, 0, 0, 0);
            d1 = __builtin_amdgcn_mfma_f32_16x16x32_bf16(af, bfr[1][ch], d1, 0, 0, 0);
        }
#pragma unroll
        for (int i = 0; i < 4; ++i) {
            const int row = r0 + kgrp * 4 + i;
            ht[(size_t)row * DH + c0 + lrow]      = f2fp8(d0[i]);
            ht[(size_t)row * DH + c0 + 16 + lrow] = f2fp8(d1[i]);
        }
    }
}

// ---- final gather: half-wave per edge (32 lanes x 4B = full 128B row),
//      2 edges per wave-instruction, 4 pairs (8 edges) in flight, fused relu+mean ----
__global__ __launch_bounds__(256) void gather_final(
        const uint8_t* __restrict__ htA, const int* __restrict__ ptrA,
        const unsigned* __restrict__ pairA, const float* __restrict__ rinA,
        const float* __restrict__ bA,
        const uint8_t* __restrict__ htB, const int* __restrict__ ptrB,
        const unsigned* __restrict__ pairB, const float* __restrict__ rinB,
        const float* __restrict__ bB,
        float* __restrict__ partsum, int n, float invn) {
    const int low  = blockIdx.x & 7;
    const int rel  = low >> 2;                  // XCDs 0-3: rel A, 4-7: rel B
    const int bid  = (blockIdx.x >> 3) * 4 + (low & 3);
    const uint8_t* __restrict__ ht = rel ? htB : htA;
    const int* __restrict__ ptr  = rel ? ptrB : ptrA;
    const unsigned* __restrict__ pair = rel ? pairB : pairA;
    const float* __restrict__ rin = rel ? rinB : rinA;
    const float* __restrict__ b   = rel ? bB : bA;

    const int gw   = (bid * blockDim.x + threadIdx.x) >> 6;
    const int nw   = (GGRID * blockDim.x) >> 6;
    const int lane = threadIdx.x & 63;
    const int eh   = lane >> 5;                 // which edge of the pair
    const int lc   = lane & 31;
    const unsigned coff = (unsigned)(lc << 2);  // 4 fp8 cols per lane
    const float4 bv = *reinterpret_cast<const float4*>(&b[lc << 2]);
    float m0 = 0.f, m1 = 0.f, m2 = 0.f, m3 = 0.f;

    for (int node = gw; node < n; node += nw) {
        const int beg = ptr[node], end = ptr[node + 1];
        float a0[4] = {0.f, 0.f, 0.f, 0.f}, a1[4] = {0.f, 0.f, 0.f, 0.f};
        float a2[4] = {0.f, 0.f, 0.f, 0.f}, a3[4] = {0.f, 0.f, 0.f, 0.f};
        int j = beg;
        if ((j & 1) && j < end) {               // peel leading odd edge (align uint2)
            if (eh == 0) {
                unsigned p = pair[j];
                unsigned hv = *reinterpret_cast<const unsigned*>(&ht[((size_t)(p & 0xffffu) << 7) + coff]);
                f32x4 d = fp8x4f(hv);
                float w = bf_hi(p);
                a0[0] = fmaf(d.x, w, a0[0]); a1[0] = fmaf(d.y, w, a1[0]);
                a2[0] = fmaf(d.z, w, a2[0]); a3[0] = fmaf(d.w, w, a3[0]);
            }
            ++j;
        }
        for (; j + 7 < end; j += 8) {           // 4 pairs = 8 edges in flight
            unsigned pe[4], hv[4];
#pragma unroll
            for (int u = 0; u < 4; ++u) {
                uint2 pp = *reinterpret_cast<const uint2*>(&pair[j + 2 * u]);
                pe[u] = eh ? pp.y : pp.x;
            }
#pragma unroll
            for (int u = 0; u < 4; ++u)
                hv[u] = *reinterpret_cast<const unsigned*>(&ht[((size_t)(pe[u] & 0xffffu) << 7) + coff]);
#pragma unroll
            for (int u = 0; u < 4; ++u) {
                f32x4 d = fp8x4f(hv[u]);
                float w = bf_hi(pe[u]);
                a0[u] = fmaf(d.x, w, a0[u]); a1[u] = fmaf(d.y, w, a1[u]);
                a2[u] = fmaf(d.z, w, a2[u]); a3[u] = fmaf(d.w, w, a3[u]);
            }
        }
        for (; j + 1 < end; j += 2) {           // aligned pair tail
            uint2 pp = *reinterpret_cast<const uint2*>(&pair[j]);
            unsigned p = eh ? pp.y : pp.x;
            unsigned hv = *reinterpret_cast<const unsigned*>(&ht[((size_t)(p & 0xffffu) << 7) + coff]);
            f32x4 d = fp8x4f(hv);
            float w = bf_hi(p);
            a0[0] = fmaf(d.x, w, a0[0]); a1[0] = fmaf(d.y, w, a1[0]);
            a2[0] = fmaf(d.z, w, a2[0]); a3[0] = fmaf(d.w, w, a3[0]);
        }
        if (j < end && eh == 0) {               // trailing odd edge
            unsigned p = pair[j];
            unsigned hv = *reinterpret_cast<const unsigned*>(&ht[((size_t)(p & 0xffffu) << 7) + coff]);
            f32x4 d = fp8x4f(hv);
            float w = bf_hi(p);
            a0[1] = fmaf(d.x, w, a0[1]); a1[1] = fmaf(d.y, w, a1[1]);
            a2[1] = fmaf(d.z, w, a2[1]); a3[1] = fmaf(d.w, w, a3[1]);
        }
        float s0 = (a0[0] + a0[1]) + (a0[2] + a0[3]);
        float s1 = (a1[0] + a1[1]) + (a1[2] + a1[3]);
        float s2 = (a2[0] + a2[1]) + (a2[2] + a2[3]);
        float s3 = (a3[0] + a3[1]) + (a3[2] + a3[3]);
        s0 += __shfl_xor(s0, 32);               // combine edge-halves
        s1 += __shfl_xor(s1, 32);
        s2 += __shfl_xor(s2, 32);
        s3 += __shfl_xor(s3, 32);
        const float rv = rin[node];
        m0 += fmaxf(fmaf(rv, s0, bv.x), 0.f);
        m1 += fmaxf(fmaf(rv, s1, bv.y), 0.f);
        m2 += fmaxf(fmaf(rv, s2, bv.z), 0.f);
        m3 += fmaxf(fmaf(rv, s3, bv.w), 0.f);
    }

    __shared__ float red[4][128];
    const int wv = threadIdx.x >> 6;
    if (eh == 0) {
        red[wv][(lc << 2) + 0] = m0;
        red[wv][(lc << 2) + 1] = m1;
        red[wv][(lc << 2) + 2] = m2;
        red[wv][(lc << 2) + 3] = m3;
    }
    __syncthreads();
    if (threadIdx.x < 128) {
        float s = red[0][threadIdx.x] + red[1][threadIdx.x]
                + red[2][threadIdx.x] + red[3][threadIdx.x];
        partsum[(size_t)blockIdx.x * DH + threadIdx.x] = s * invn;
    }
}

// ---- sum partial rows into out[0..127] ----
__global__ void reduce_out(const float* __restrict__ partial, float* __restrict__ out, int nrows) {
    const int t = threadIdx.x;                 // 128
    const int per = nrows / gridDim.x;
    const int b0 = blockIdx.x * per;
    float s = 0.f;
    for (int b = b0; b < b0 + per; ++b) s += partial[(size_t)b * DH + t];
    atomicAdd(&out[t], s);
}

extern "C" void kernel_launch(void* const* d_in, const int* in_sizes, int n_in,
                              void* d_out, int out_size, void* d_ws, size_t ws_size,
                              hipStream_t stream) {
    const float* feat_row = (const float*)d_in[0];
    const float* feat_col = (const float*)d_in[1];
    const int*   src_rc   = (const int*)d_in[2];
    const int*   dst_rc   = (const int*)d_in[3];
    const float* w_rc     = (const float*)d_in[4];
    const int*   src_cr   = (const int*)d_in[5];
    const int*   dst_cr   = (const int*)d_in[6];
    const float* w_cr     = (const float*)d_in[7];
    const float* W0_rc    = (const float*)d_in[8];
    const float* b0_rc    = (const float*)d_in[9];
    const float* W0_cr    = (const float*)d_in[10];
    const float* b0_cr    = (const float*)d_in[11];
    const float* W1_rc    = (const float*)d_in[12];
    const float* b1_rc    = (const float*)d_in[13];
    const float* W1_cr    = (const float*)d_in[14];
    const float* b1_cr    = (const float*)d_in[15];
    const int E = in_sizes[2];
    float* out = (float*)d_out;

    // ---- workspace layout (~75 MB) ----
    int*   cnt     = (int*)d_ws;                        // 200000
    float* norms   = (float*)(cnt + 200000);            // 200000
    int*   ptr_rc  = (int*)(norms + 200000);            // 50004
    int*   ptr_cr  = ptr_rc + 50004;                    // 50004
    int*   bsum    = ptr_cr + 50004;                    // 200
    int*   cbase   = bsum + 200;                        // 216 (pad)
    unsigned* pair_rc = (unsigned*)(cbase + 216);       // E
    unsigned* pair_cr = pair_rc + E;                    // E
    unsigned short* agg_col = (unsigned short*)(pair_cr + E);       // 50000*64 bf16
    unsigned short* agg_row = agg_col + (size_t)NCOL * 64;          // 50000*64 bf16
    uint8_t* f8_row = (uint8_t*)(agg_row + (size_t)NROW * 64);      // 50000*64 fp8
    uint8_t* f8_col = f8_row + (size_t)NROW * 64;                   // 50000*64 fp8
    unsigned short* h_col1 = (unsigned short*)(f8_col + (size_t)NCOL * 64); // 50000*128 bf16
    unsigned short* h_row1 = h_col1 + (size_t)NCOL * DH;                    // 50000*128 bf16
    uint8_t* ht_row = (uint8_t*)(h_row1 + (size_t)NROW * DH);       // 50000*128 fp8
    uint8_t* ht_col = ht_row + (size_t)NROW * DH;                   // 50000*128 fp8
    float* partsum = (float*)(ht_col + (size_t)NCOL * DH);          // 2*GGRID*128 fp32
    unsigned short* wt = (unsigned short*)(partsum + (size_t)2 * GGRID * DH); // 49152
    // CSR-build aliases (dead before gathers/prep): u16 partial (12.8 MB) + int bstart (12.8 MB)
    unsigned short* partial = (unsigned short*)agg_col;             // 16*HBLK*HB u16
    int* bstart = (int*)(partial + (size_t)16 * HBLK * HB);         // 8*HBLK*HB int

    float* r_out_rc = norms;
    float* r_in_rc  = norms + NROW;
    float* r_out_cr = norms + NROW + NCOL;
    float* r_in_cr  = norms + NROW + 2 * NCOL;

    unsigned short* wt0_rc = wt;
    unsigned short* wt0_cr = wt + 8192;
    unsigned short* wt1_rc = wt + 16384;
    unsigned short* wt1_cr = wt + 32768;

    // ---- CSR build (aliases live here) ----
    hist_lds<<<16 * HBLK, 1024, 0, stream>>>(src_rc, dst_rc, src_cr, dst_cr, partial, E);
    reduce_norms2<<<512, 256, 0, stream>>>(partial, cnt, norms);
    scanA<<<200, 256, 0, stream>>>(cnt, bsum);
    scanB<<<1, 256, 0, stream>>>(bsum, cbase);
    scanC<<<200, 512, 0, stream>>>(cnt, cbase, ptr_rc, ptr_cr, E);
    block_starts<<<400, 256, 0, stream>>>(partial, bstart, ptr_rc, ptr_cr);
    csr_fill_sorted<<<8 * HBLK, 1024, 0, stream>>>(
        src_rc, dst_rc, w_rc, r_out_rc, pair_rc,
        src_cr, dst_cr, w_cr, r_out_cr, pair_cr, bstart, E);

    // ---- fp8 feature tables + bf16 weights (aliases now dead) ----
    prep_tables<<<2048, 256, 0, stream>>>((const float4*)feat_row, (const float4*)feat_col,
                                          (unsigned*)f8_row, (unsigned*)f8_col, NROW * 64 / 4,
                                          W0_rc, W0_cr, W1_rc, W1_cr, wt);

    // ---- layer 1 ----
    gather64_2<<<2 * GGRID, 256, 0, stream>>>(f8_row, ptr_rc, pair_rc, agg_col,
                                              f8_col, ptr_cr, pair_cr, agg_row, NCOL);
    dense64_2<<<2 * DGRID, 256, 0, stream>>>(agg_col, r_in_rc, wt0_rc, b0_rc, h_col1,
                                             agg_row, r_in_cr, wt0_cr, b0_cr, h_row1, NCOL);

    // ---- layer 2: pre-transform h1@W1 -> fp8, then fused gather+relu+mean ----
    h1t_gemm2<<<2 * DGRID, 256, 0, stream>>>(h_row1, wt1_rc, ht_row,
                                             h_col1, wt1_cr, ht_col, NROW);
    hipMemsetAsync(out, 0, DH * sizeof(float), stream);
    gather_final<<<2 * GGRID, 256, 0, stream>>>(
        ht_row, ptr_rc, pair_rc, r_in_rc, b1_rc,
        ht_col, ptr_cr, pair_cr, r_in_cr, b1_cr,
        partsum, NCOL, 1.0f / NCOL);
    reduce_out<<<32, 128, 0, stream>>>(partsum, out, 2 * GGRID);
}

// Round 19
// 285.317 us; speedup vs baseline: 1.2162x; 1.0008x over previous
//
#include <hip/hip_runtime.h>
#include <stdint.h>

constexpr int NROW = 50000;
constexpr int NCOL = 50000;
constexpr int DH   = 128;
constexpr int NTAB = 200000;   // [out_rc(NROW) | in_rc(NCOL) | out_cr(NCOL) | in_cr(NROW)]
constexpr int HB   = 12500;    // bins per section (quarter table), 50 KB LDS
constexpr int HBLK = 32;       // blocks per section (1024-thread blocks)
constexpr int DGRID = 1250;    // dense blocks per relation
constexpr int GGRID = 2048;    // gather blocks per relation
constexpr int CH    = 500;     // scan chunk size (100 chunks per table)
constexpr int PBLK  = 512;     // prep blocks fused into csr_fill launch

typedef __attribute__((ext_vector_type(8))) short short8;
typedef __attribute__((ext_vector_type(4))) float f32x4;
typedef __attribute__((ext_vector_type(2))) float f32x2;

__device__ __forceinline__ float bf_hi(unsigned u) { return __uint_as_float(u & 0xffff0000u); }
__device__ __forceinline__ unsigned short f2bf(float f) {   // RNE
    unsigned u = __float_as_uint(f);
    return (unsigned short)((u + 0x7fffu + ((u >> 16) & 1u)) >> 16);
}

// ---- fp8 OCP e4m3fn encode (RNE, clamp 448, subnormal-aware) ----
__device__ __forceinline__ unsigned char f2fp8(float f) {
    unsigned b = __float_as_uint(f);
    unsigned s = (b >> 24) & 0x80u;
    unsigned mag = b & 0x7fffffffu;
    if (mag >= 0x43e00000u) return (unsigned char)(s | 0x7eu);   // clamp to ±448
    unsigned r = mag + 0x7ffffu + ((mag >> 20) & 1u);
    int e = (int)(r >> 23) - 120;
    if (e < 1) {                                                  // subnormal: m * 2^-9
        float af = __uint_as_float(mag);
        unsigned m = (unsigned)(af * 512.f + 0.5f);
        if (m > 8u) m = 8u;
        return (unsigned char)(s | m);
    }
    return (unsigned char)(s | (unsigned)(e << 3) | ((r >> 20) & 7u));
}

// ---- fp8 decode helpers (HW cvt if available) ----
#if defined(__has_builtin) && __has_builtin(__builtin_amdgcn_cvt_pk_f32_fp8)
__device__ __forceinline__ f32x2 fp8x2f(unsigned v) {
    return __builtin_amdgcn_cvt_pk_f32_fp8((int)v, false);
}
__device__ __forceinline__ f32x4 fp8x4f(unsigned v) {
    f32x2 lo = __builtin_amdgcn_cvt_pk_f32_fp8((int)v, false);
    f32x2 hi = __builtin_amdgcn_cvt_pk_f32_fp8((int)v, true);
    f32x4 r; r.x = lo.x; r.y = lo.y; r.z = hi.x; r.w = hi.y; return r;
}
#else
__device__ __forceinline__ float fp8_1(unsigned u) {
    unsigned s = (u & 0x80u) << 24, em = u & 0x7fu;
    if (em >= 8u) return __uint_as_float(s | ((em + 960u) << 20));
    float v = (float)em * 0.001953125f;
    return (u & 0x80u) ? -v : v;
}
__device__ __forceinline__ f32x2 fp8x2f(unsigned v) {
    f32x2 r; r.x = fp8_1(v & 0xffu); r.y = fp8_1((v >> 8) & 0xffu); return r;
}
__device__ __forceinline__ f32x4 fp8x4f(unsigned v) {
    f32x4 r; r.x = fp8_1(v & 0xffu); r.y = fp8_1((v >> 8) & 0xffu);
    r.z = fp8_1((v >> 16) & 0xffu); r.w = fp8_1((v >> 24) & 0xffu); return r;
}
#endif

// ---- degree histograms via LDS privatization; u16 partials; 1024-thread blocks ----
__global__ __launch_bounds__(1024) void hist_lds(
        const int* __restrict__ s_rc, const int* __restrict__ d_rc,
        const int* __restrict__ s_cr, const int* __restrict__ d_cr,
        unsigned short* __restrict__ partial, int E) {
    __shared__ int h[HB];
    const int sec = blockIdx.x >> 5;           // 0..15
    const int blk = blockIdx.x & (HBLK - 1);   // 0..31
    const int tab = sec >> 2;                  // 0..3 -> array
    const int lo  = (sec & 3) * HB;
    const int* __restrict__ arr = (tab == 0) ? s_rc : (tab == 1) ? d_rc
                                 : (tab == 2) ? s_cr : d_cr;
    for (int i = threadIdx.x; i < HB; i += blockDim.x) h[i] = 0;
    __syncthreads();
    const int stride = HBLK * blockDim.x;
    for (int i = blk * blockDim.x + threadIdx.x; i < E; i += stride) {
        int id = arr[i] - lo;
        if ((unsigned)id < (unsigned)HB) atomicAdd(&h[id], 1);   // LDS atomic
    }
    __syncthreads();
    unsigned short* __restrict__ out = partial + ((size_t)sec * HBLK + blk) * HB;
    for (int i = threadIdx.x; i < HB; i += blockDim.x) out[i] = (unsigned short)h[i];
}

// ---- reduce HBLK u16 partials/section -> cnt + norms ----
__global__ void reduce_norms2(const unsigned short* __restrict__ partial, int* __restrict__ cnt,
                              float* __restrict__ norms) {
    int stride = gridDim.x * blockDim.x;
    for (int i = blockIdx.x * blockDim.x + threadIdx.x; i < NTAB; i += stride) {
        int t = i / 50000;
        int r = i - t * 50000;
        int q = r / HB;
        int j = r - q * HB;
        const unsigned short* __restrict__ p = partial + ((size_t)(t * 4 + q) * HBLK) * HB + j;
        int s = 0;
#pragma unroll
        for (int b = 0; b < HBLK; ++b) s += p[(size_t)b * HB];
        cnt[i] = s;
        norms[i] = 1.0f / sqrtf((float)max(s, 1));
    }
}

// ---- parallel exclusive scan of the two dst-count tables, 3 phases ----
__global__ __launch_bounds__(256) void scanA(const int* __restrict__ cnt, int* __restrict__ bsum) {
    __shared__ int red[256];
    const int c = blockIdx.x;
    const int* __restrict__ cbl = cnt + ((c >= 100) ? 150000 : 50000);
    const int j0 = (c % 100) * CH;
    int s = 0;
    for (int i = threadIdx.x; i < CH; i += 256) s += cbl[j0 + i];
    red[threadIdx.x] = s;
    __syncthreads();
    for (int off = 128; off > 0; off >>= 1) {
        if (threadIdx.x < off) red[threadIdx.x] += red[threadIdx.x + off];
        __syncthreads();
    }
    if (threadIdx.x == 0) bsum[c] = red[0];
}

__global__ void scanB(const int* __restrict__ bsum, int* __restrict__ cbase) {
    __shared__ int b[200];
    for (int i = threadIdx.x; i < 200; i += blockDim.x) b[i] = bsum[i];
    __syncthreads();
    if (threadIdx.x < 2) {
        int run = 0;
        const int o = threadIdx.x * 100;
        for (int k = 0; k < 100; ++k) { cbase[o + k] = run; run += b[o + k]; }
    }
}

__global__ __launch_bounds__(512) void scanC(const int* __restrict__ cnt,
                                             const int* __restrict__ cbase,
                                             int* __restrict__ ptr_rc, int* __restrict__ ptr_cr,
                                             int E) {
    __shared__ int buf[512];
    const int c = blockIdx.x;
    const int table = (c >= 100);
    const int* __restrict__ cbl = cnt + (table ? 150000 : 50000);
    int* __restrict__ ptr = table ? ptr_cr : ptr_rc;
    const int j0 = (c % 100) * CH;
    const int t = threadIdx.x;
    const int v = (t < CH) ? cbl[j0 + t] : 0;
    buf[t] = v;
    __syncthreads();
    for (int off = 1; off < 512; off <<= 1) {
        int tmp = (t >= off) ? buf[t - off] : 0;
        __syncthreads();
        buf[t] += tmp;
        __syncthreads();
    }
    if (t < CH) ptr[j0 + t] = cbase[c] + buf[t] - v;
    if ((c % 100) == 99 && t == 0) ptr[50000] = E;
}

// ---- dst-section u16 partials -> absolute int block start positions ----
__global__ void block_starts(const unsigned short* __restrict__ partial, int* __restrict__ bstart,
                             const int* __restrict__ ptr_rc, const int* __restrict__ ptr_cr) {
    int stride = gridDim.x * blockDim.x;
    for (int i = blockIdx.x * blockDim.x + threadIdx.x; i < 8 * HB; i += stride) {
        int fsec = i / HB;                 // 0..7 = (rel, quarter)
        int j = i - fsec * HB;
        int rel = fsec >> 2, q = fsec & 3;
        int histsec = rel * 8 + 4 + q;     // dst tab = rel*2+1
        const int* __restrict__ ptr = rel ? ptr_cr : ptr_rc;
        int run = ptr[q * HB + j];
        const unsigned short* __restrict__ p = partial + ((size_t)histsec * HBLK) * HB + j;
        int* __restrict__ o = bstart + ((size_t)fsec * HBLK) * HB + j;
#pragma unroll
        for (int b = 0; b < HBLK; ++b) {
            o[(size_t)b * HB] = run;
            run += p[(size_t)b * HB];
        }
    }
}

// ---- FUSED: CSR fill (blocks 0..255, XCD-affine, latency-bound) +
//             prep tables (blocks 256.., streaming, fills idle issue slots) ----
__global__ __launch_bounds__(1024) void csr_fill_prep(
        const int* __restrict__ sA, const int* __restrict__ dA,
        const float* __restrict__ wA, const float* __restrict__ routA, unsigned* __restrict__ pairA,
        const int* __restrict__ sB, const int* __restrict__ dB,
        const float* __restrict__ wB, const float* __restrict__ routB, unsigned* __restrict__ pairB,
        const int* __restrict__ bstart, int E,
        const float4* __restrict__ fr, const float4* __restrict__ fc,
        unsigned* __restrict__ f8r, unsigned* __restrict__ f8c, int nq,
        const float* __restrict__ W0a, const float* __restrict__ W0b,
        const float* __restrict__ W1a, const float* __restrict__ W1b,
        unsigned short* __restrict__ wt) {
    __shared__ int offs[HB];
    if (blockIdx.x < 8 * HBLK) {
        // ---- csr fill ----
        const int fsec = blockIdx.x & 7;           // section -> XCD
        const int blk  = blockIdx.x >> 3;          // 0..31
        const int rel = fsec >> 2, q = fsec & 3;
        const int lo = q * HB;
        const int* __restrict__ src  = rel ? sB : sA;
        const int* __restrict__ dst  = rel ? dB : dA;
        const float* __restrict__ w  = rel ? wB : wA;
        const float* __restrict__ ro = rel ? routB : routA;
        unsigned* __restrict__ pair  = rel ? pairB : pairA;
        const int* __restrict__ bs = bstart + ((size_t)fsec * HBLK + blk) * HB;
        for (int i = threadIdx.x; i < HB; i += blockDim.x) offs[i] = bs[i];
        __syncthreads();
        const int stride = HBLK * blockDim.x;
        for (int i = blk * blockDim.x + threadIdx.x; i < E; i += stride) {
            int id = dst[i] - lo;
            if ((unsigned)id < (unsigned)HB) {
                int pos = atomicAdd(&offs[id], 1);        // LDS atomic
                int s = src[i];
                pair[pos] = (unsigned)s | ((unsigned)f2bf(w[i] * ro[s]) << 16);
            }
        }
    } else {
        // ---- prep tables (independent of CSR chain) ----
        const int bid = blockIdx.x - 8 * HBLK;
        const int total = 2 * nq + 49152;
        const int stride = PBLK * 1024;
        for (int i = bid * 1024 + threadIdx.x; i < total; i += stride) {
            if (i < 2 * nq) {
                bool second = i >= nq;
                int k = second ? i - nq : i;
                float4 v = second ? fc[k] : fr[k];
                unsigned o = (unsigned)f2fp8(v.x) | ((unsigned)f2fp8(v.y) << 8)
                           | ((unsigned)f2fp8(v.z) << 16) | ((unsigned)f2fp8(v.w) << 24);
                if (second) f8c[k] = o; else f8r[k] = o;
            } else {
                int j = i - 2 * nq;
                const float* W; int K, base;
                if (j < 8192)       { W = W0a; K = 64;  base = 0; }
                else if (j < 16384) { W = W0b; K = 64;  base = 8192;  j -= 8192; }
                else if (j < 32768) { W = W1a; K = 128; base = 16384; j -= 16384; }
                else                { W = W1b; K = 128; base = 32768; j -= 32768; }
                int n = j / K, k = j - n * K;
                wt[base + n * K + k] = f2bf(W[k * DH + n]);
            }
        }
    }
}

// ---- D=64 gather from fp8 tables, XCD-affine relation split, 8 edges/half in flight ----
__global__ void gather64_2(const uint8_t* __restrict__ hA, const int* __restrict__ ptrA,
                           const unsigned* __restrict__ pairA, unsigned short* __restrict__ aggA,
                           const uint8_t* __restrict__ hB, const int* __restrict__ ptrB,
                           const unsigned* __restrict__ pairB, unsigned short* __restrict__ aggB,
                           int n) {
    const int low  = blockIdx.x & 7;
    const int rel  = low >> 2;                  // XCDs 0-3: rel A, 4-7: rel B
    const int bid  = (blockIdx.x >> 3) * 4 + (low & 3);
    const uint8_t* __restrict__ h = rel ? hB : hA;
    const int* __restrict__ ptr  = rel ? ptrB : ptrA;
    const unsigned* __restrict__ pair = rel ? pairB : pairA;
    unsigned short* __restrict__ agg  = rel ? aggB : aggA;
    const int gw   = (bid * blockDim.x + threadIdx.x) >> 6;
    const int nw   = (GGRID * blockDim.x) >> 6;
    const int lane = threadIdx.x & 63;
    const int half = lane >> 5;
    const int c    = (lane & 31) << 1;          // column pair 0..62 (byte offset too)
    for (int node = gw; node < n; node += nw) {
        const int beg = ptr[node], end = ptr[node + 1];
        float ax[8], ay[8];
#pragma unroll
        for (int u = 0; u < 8; ++u) { ax[u] = 0.f; ay[u] = 0.f; }
        int j = beg + half;
        for (; j + 14 < end; j += 16) {         // 8 edges per half-wave in flight
            unsigned p[8], hv[8];
#pragma unroll
            for (int u = 0; u < 8; ++u) p[u] = pair[j + 2 * u];
#pragma unroll
            for (int u = 0; u < 8; ++u)
                hv[u] = *reinterpret_cast<const unsigned short*>(&h[((p[u] & 0xffffu) << 6) + c]);
#pragma unroll
            for (int u = 0; u < 8; ++u) {
                f32x2 d = fp8x2f(hv[u]);
                float w = bf_hi(p[u]);
                ax[u] = fmaf(d.x, w, ax[u]); ay[u] = fmaf(d.y, w, ay[u]);
            }
        }
        for (; j < end; j += 2) {
            unsigned p = pair[j];
            unsigned hv = *reinterpret_cast<const unsigned short*>(&h[((p & 0xffffu) << 6) + c]);
            f32x2 d = fp8x2f(hv);
            float w = bf_hi(p);
            ax[0] = fmaf(d.x, w, ax[0]); ay[0] = fmaf(d.y, w, ay[0]);
        }
        float ax_ = ((ax[0] + ax[1]) + (ax[2] + ax[3])) + ((ax[4] + ax[5]) + (ax[6] + ax[7]));
        float ay_ = ((ay[0] + ay[1]) + (ay[2] + ay[3])) + ((ay[4] + ay[5]) + (ay[6] + ay[7]));
        ax_ += __shfl_xor(ax_, 32);
        ay_ += __shfl_xor(ay_, 32);
        if (half == 0) {
            unsigned pk = (unsigned)f2bf(ax_) | ((unsigned)f2bf(ay_) << 16);
            *reinterpret_cast<unsigned*>(&agg[(size_t)node * 64 + c]) = pk;
        }
    }
}

// ---- layer-1 dense via MFMA 16x16x32 bf16, both relations fused ----
__global__ __launch_bounds__(256) void dense64_2(
        const unsigned short* __restrict__ aggA, const float* __restrict__ rinA,
        const unsigned short* __restrict__ wtA, const float* __restrict__ bA,
        unsigned short* __restrict__ outA,
        const unsigned short* __restrict__ aggB, const float* __restrict__ rinB,
        const unsigned short* __restrict__ wtB, const float* __restrict__ bB,
        unsigned short* __restrict__ outB, int n) {
    constexpr int K = 64, NCH = 2;
    const int rel = blockIdx.x >= DGRID;
    const int bid = rel ? blockIdx.x - DGRID : blockIdx.x;
    const unsigned short* __restrict__ agg = rel ? aggB : aggA;
    const float* __restrict__ rin = rel ? rinB : rinA;
    const unsigned short* __restrict__ wt = rel ? wtB : wtA;
    const float* __restrict__ b = rel ? bB : bA;
    unsigned short* __restrict__ outbf = rel ? outB : outA;

    const int wave = threadIdx.x >> 6;
    const int lane = threadIdx.x & 63;
    const int lrow = lane & 15;
    const int kgrp = lane >> 4;
    const int c0   = wave * 32;

    short8 bfr[2][NCH];
#pragma unroll
    for (int t = 0; t < 2; ++t)
#pragma unroll
        for (int ch = 0; ch < NCH; ++ch)
            bfr[t][ch] = *reinterpret_cast<const short8*>(
                &wt[(size_t)(c0 + t * 16 + lrow) * K + ch * 32 + kgrp * 8]);

    const float bias0 = b[c0 + lrow], bias1 = b[c0 + 16 + lrow];
    const int nstrip = n >> 4;
    for (int s = bid; s < nstrip; s += DGRID) {
        const int r0 = s << 4;
        f32x4 d0 = {0.f, 0.f, 0.f, 0.f}, d1 = {0.f, 0.f, 0.f, 0.f};
#pragma unroll
        for (int ch = 0; ch < NCH; ++ch) {
            short8 af = *reinterpret_cast<const short8*>(
                &agg[(size_t)(r0 + lrow) * K + ch * 32 + kgrp * 8]);
            d0 = __builtin_amdgcn_mfma_f32_16x16x32_bf16(af, bfr[0][ch], d0, 0, 0, 0);
            d1 = __builtin_amdgcn_mfma_f32_16x16x32_bf16(af, bfr[1][ch], d1, 0, 0, 0);
        }
#pragma unroll
        for (int i = 0; i < 4; ++i) {          // C/D: col=lane&15, row=(lane>>4)*4+i
            const int row = r0 + kgrp * 4 + i;
            const float rv = rin[row];
            outbf[(size_t)row * DH + c0 + lrow]      = f2bf(fmaxf(fmaf(rv, d0[i], bias0), 0.f));
            outbf[(size_t)row * DH + c0 + 16 + lrow] = f2bf(fmaxf(fmaf(rv, d1[i], bias1), 0.f));
        }
    }
}

// ---- h1t = h1 @ W1 -> fp8 tables (pre-transform; both relations fused) ----
__global__ __launch_bounds__(256) void h1t_gemm2(
        const unsigned short* __restrict__ hA, const unsigned short* __restrict__ wtA,
        uint8_t* __restrict__ htA,
        const unsigned short* __restrict__ hB, const unsigned short* __restrict__ wtB,
        uint8_t* __restrict__ htB, int n) {
    constexpr int K = 128, NCH = 4;
    const int rel = blockIdx.x >= DGRID;
    const int bid = rel ? blockIdx.x - DGRID : blockIdx.x;
    const unsigned short* __restrict__ h = rel ? hB : hA;
    const unsigned short* __restrict__ wt = rel ? wtB : wtA;
    uint8_t* __restrict__ ht = rel ? htB : htA;

    const int wave = threadIdx.x >> 6;
    const int lane = threadIdx.x & 63;
    const int lrow = lane & 15;
    const int kgrp = lane >> 4;
    const int c0   = wave * 32;

    short8 bfr[2][NCH];
#pragma unroll
    for (int t = 0; t < 2; ++t)
#pragma unroll
        for (int ch = 0; ch < NCH; ++ch)
            bfr[t][ch] = *reinterpret_cast<const short8*>(
                &wt[(size_t)(c0 + t * 16 + lrow) * K + ch * 32 + kgrp * 8]);

    const int nstrip = n >> 4;
    for (int s = bid; s < nstrip; s += DGRID) {
        const int r0 = s << 4;
        f32x4 d0 = {0.f, 0.f, 0.f, 0.f}, d1 = {0.f, 0.f, 0.f, 0.f};
#pragma unroll
        for (int ch = 0; ch < NCH; ++ch) {
            short8 af = *reinterpret_cast<const short8*>(
                &h[(size_t)(r0 + lrow) * K + ch * 32 + kgrp * 8]);
            d0 = __builtin_amdgcn_mfma_f32_16x16x32_bf16(af, bfr[0][ch], d0, 0, 0, 0);
            d1 = __builtin_amdgcn_mfma_f32_16x16x32_bf16(af, bfr[1][ch], d1, 0, 0, 0);
        }
#pragma unroll
        for (int i = 0; i < 4; ++i) {
            const int row = r0 + kgrp * 4 + i;
            ht[(size_t)row * DH + c0 + lrow]      = f2fp8(d0[i]);
            ht[(size_t)row * DH + c0 + 16 + lrow] = f2fp8(d1[i]);
        }
    }
}

// ---- final gather: half-wave per edge (32 lanes x 4B = full 128B row),
//      2 edges per wave-instruction, 4 pairs (8 edges) in flight, fused relu+mean ----
__global__ __launch_bounds__(256) void gather_final(
        const uint8_t* __restrict__ htA, const int* __restrict__ ptrA,
        const unsigned* __restrict__ pairA, const float* __restrict__ rinA,
        const float* __restrict__ bA,
        const uint8_t* __restrict__ htB, const int* __restrict__ ptrB,
        const unsigned* __restrict__ pairB, const float* __restrict__ rinB,
        const float* __restrict__ bB,
        float* __restrict__ partsum, int n, float invn) {
    const int low  = blockIdx.x & 7;
    const int rel  = low >> 2;                  // XCDs 0-3: rel A, 4-7: rel B
    const int bid  = (blockIdx.x >> 3) * 4 + (low & 3);
    const uint8_t* __restrict__ ht = rel ? htB : htA;
    const int* __restrict__ ptr  = rel ? ptrB : ptrA;
    const unsigned* __restrict__ pair = rel ? pairB : pairA;
    const float* __restrict__ rin = rel ? rinB : rinA;
    const float* __restrict__ b   = rel ? bB : bA;

    const int gw   = (bid * blockDim.x + threadIdx.x) >> 6;
    const int nw   = (GGRID * blockDim.x) >> 6;
    const int lane = threadIdx.x & 63;
    const int eh   = lane >> 5;                 // which edge of the pair
    const int lc   = lane & 31;
    const unsigned coff = (unsigned)(lc << 2);  // 4 fp8 cols per lane
    const float4 bv = *reinterpret_cast<const float4*>(&b[lc << 2]);
    float m0 = 0.f, m1 = 0.f, m2 = 0.f, m3 = 0.f;

    for (int node = gw; node < n; node += nw) {
        const int beg = ptr[node], end = ptr[node + 1];
        float a0[4] = {0.f, 0.f, 0.f, 0.f}, a1[4] = {0.f, 0.f, 0.f, 0.f};
        float a2[4] = {0.f, 0.f, 0.f, 0.f}, a3[4] = {0.f, 0.f, 0.f, 0.f};
        int j = beg;
        if ((j & 1) && j < end) {               // peel leading odd edge (align uint2)
            if (eh == 0) {
                unsigned p = pair[j];
                unsigned hv = *reinterpret_cast<const unsigned*>(&ht[((size_t)(p & 0xffffu) << 7) + coff]);
                f32x4 d = fp8x4f(hv);
                float w = bf_hi(p);
                a0[0] = fmaf(d.x, w, a0[0]); a1[0] = fmaf(d.y, w, a1[0]);
                a2[0] = fmaf(d.z, w, a2[0]); a3[0] = fmaf(d.w, w, a3[0]);
            }
            ++j;
        }
        for (; j + 7 < end; j += 8) {           // 4 pairs = 8 edges in flight
            unsigned pe[4], hv[4];
#pragma unroll
            for (int u = 0; u < 4; ++u) {
                uint2 pp = *reinterpret_cast<const uint2*>(&pair[j + 2 * u]);
                pe[u] = eh ? pp.y : pp.x;
            }
#pragma unroll
            for (int u = 0; u < 4; ++u)
                hv[u] = *reinterpret_cast<const unsigned*>(&ht[((size_t)(pe[u] & 0xffffu) << 7) + coff]);
#pragma unroll
            for (int u = 0; u < 4; ++u) {
                f32x4 d = fp8x4f(hv[u]);
                float w = bf_hi(pe[u]);
                a0[u] = fmaf(d.x, w, a0[u]); a1[u] = fmaf(d.y, w, a1[u]);
                a2[u] = fmaf(d.z, w, a2[u]); a3[u] = fmaf(d.w, w, a3[u]);
            }
        }
        for (; j + 1 < end; j += 2) {           // aligned pair tail
            uint2 pp = *reinterpret_cast<const uint2*>(&pair[j]);
            unsigned p = eh ? pp.y : pp.x;
            unsigned hv = *reinterpret_cast<const unsigned*>(&ht[((size_t)(p & 0xffffu) << 7) + coff]);
            f32x4 d = fp8x4f(hv);
            float w = bf_hi(p);
            a0[0] = fmaf(d.x, w, a0[0]); a1[0] = fmaf(d.y, w, a1[0]);
            a2[0] = fmaf(d.z, w, a2[0]); a3[0] = fmaf(d.w, w, a3[0]);
        }
        if (j < end && eh == 0) {               // trailing odd edge
            unsigned p = pair[j];
            unsigned hv = *reinterpret_cast<const unsigned*>(&ht[((size_t)(p & 0xffffu) << 7) + coff]);
            f32x4 d = fp8x4f(hv);
            float w = bf_hi(p);
            a0[1] = fmaf(d.x, w, a0[1]); a1[1] = fmaf(d.y, w, a1[1]);
            a2[1] = fmaf(d.z, w, a2[1]); a3[1] = fmaf(d.w, w, a3[1]);
        }
        float s0 = (a0[0] + a0[1]) + (a0[2] + a0[3]);
        float s1 = (a1[0] + a1[1]) + (a1[2] + a1[3]);
        float s2 = (a2[0] + a2[1]) + (a2[2] + a2[3]);
        float s3 = (a3[0] + a3[1]) + (a3[2] + a3[3]);
        s0 += __shfl_xor(s0, 32);               // combine edge-halves
        s1 += __shfl_xor(s1, 32);
        s2 += __shfl_xor(s2, 32);
        s3 += __shfl_xor(s3, 32);
        const float rv = rin[node];
        m0 += fmaxf(fmaf(rv, s0, bv.x), 0.f);
        m1 += fmaxf(fmaf(rv, s1, bv.y), 0.f);
        m2 += fmaxf(fmaf(rv, s2, bv.z), 0.f);
        m3 += fmaxf(fmaf(rv, s3, bv.w), 0.f);
    }

    __shared__ float red[4][128];
    const int wv = threadIdx.x >> 6;
    if (eh == 0) {
        red[wv][(lc << 2) + 0] = m0;
        red[wv][(lc << 2) + 1] = m1;
        red[wv][(lc << 2) + 2] = m2;
        red[wv][(lc << 2) + 3] = m3;
    }
    __syncthreads();
    if (threadIdx.x < 128) {
        float s = red[0][threadIdx.x] + red[1][threadIdx.x]
                + red[2][threadIdx.x] + red[3][threadIdx.x];
        partsum[(size_t)blockIdx.x * DH + threadIdx.x] = s * invn;
    }
}

// ---- sum partial rows into out[0..127] ----
__global__ void reduce_out(const float* __restrict__ partial, float* __restrict__ out, int nrows) {
    const int t = threadIdx.x;                 // 128
    const int per = nrows / gridDim.x;
    const int b0 = blockIdx.x * per;
    float s = 0.f;
    for (int b = b0; b < b0 + per; ++b) s += partial[(size_t)b * DH + t];
    atomicAdd(&out[t], s);
}

extern "C" void kernel_launch(void* const* d_in, const int* in_sizes, int n_in,
                              void* d_out, int out_size, void* d_ws, size_t ws_size,
                              hipStream_t stream) {
    const float* feat_row = (const float*)d_in[0];
    const float* feat_col = (const float*)d_in[1];
    const int*   src_rc   = (const int*)d_in[2];
    const int*   dst_rc   = (const int*)d_in[3];
    const float* w_rc     = (const float*)d_in[4];
    const int*   src_cr   = (const int*)d_in[5];
    const int*   dst_cr   = (const int*)d_in[6];
    const float* w_cr     = (const float*)d_in[7];
    const float* W0_rc    = (const float*)d_in[8];
    const float* b0_rc    = (const float*)d_in[9];
    const float* W0_cr    = (const float*)d_in[10];
    const float* b0_cr    = (const float*)d_in[11];
    const float* W1_rc    = (const float*)d_in[12];
    const float* b1_rc    = (const float*)d_in[13];
    const float* W1_cr    = (const float*)d_in[14];
    const float* b1_cr    = (const float*)d_in[15];
    const int E = in_sizes[2];
    float* out = (float*)d_out;

    // ---- workspace layout (~84 MB); bstart now NON-aliased (prep co-runs with csr_fill) ----
    int*   cnt     = (int*)d_ws;                        // 200000
    float* norms   = (float*)(cnt + 200000);            // 200000
    int*   ptr_rc  = (int*)(norms + 200000);            // 50004
    int*   ptr_cr  = ptr_rc + 50004;                    // 50004
    int*   bsum    = ptr_cr + 50004;                    // 200
    int*   cbase   = bsum + 200;                        // 216 (pad)
    unsigned* pair_rc = (unsigned*)(cbase + 216);       // E
    unsigned* pair_cr = pair_rc + E;                    // E
    unsigned short* agg_col = (unsigned short*)(pair_cr + E);       // 50000*64 bf16
    unsigned short* agg_row = agg_col + (size_t)NCOL * 64;          // 50000*64 bf16
    uint8_t* f8_row = (uint8_t*)(agg_row + (size_t)NROW * 64);      // 50000*64 fp8
    uint8_t* f8_col = f8_row + (size_t)NROW * 64;                   // 50000*64 fp8
    unsigned short* h_col1 = (unsigned short*)(f8_col + (size_t)NCOL * 64); // 50000*128 bf16
    unsigned short* h_row1 = h_col1 + (size_t)NCOL * DH;                    // 50000*128 bf16
    uint8_t* ht_row = (uint8_t*)(h_row1 + (size_t)NROW * DH);       // 50000*128 fp8
    uint8_t* ht_col = ht_row + (size_t)NROW * DH;                   // 50000*128 fp8
    float* partsum = (float*)(ht_col + (size_t)NCOL * DH);          // 2*GGRID*128 fp32
    unsigned short* wt = (unsigned short*)(partsum + (size_t)2 * GGRID * DH); // 49152
    int* bstart = (int*)(wt + 49152);                   // 8*HBLK*HB int (dedicated, 12.8 MB)
    // hist partial (12.8 MB) aliases agg_col+agg_row (dead during CSR build)
    unsigned short* partial = (unsigned short*)agg_col; // 16*HBLK*HB u16

    float* r_out_rc = norms;
    float* r_in_rc  = norms + NROW;
    float* r_out_cr = norms + NROW + NCOL;
    float* r_in_cr  = norms + NROW + 2 * NCOL;

    unsigned short* wt0_rc = wt;
    unsigned short* wt0_cr = wt + 8192;
    unsigned short* wt1_rc = wt + 16384;
    unsigned short* wt1_cr = wt + 32768;

    hipMemsetAsync(out, 0, DH * sizeof(float), stream);

    // ---- CSR build (partial alias live until csr_fill_prep) ----
    hist_lds<<<16 * HBLK, 1024, 0, stream>>>(src_rc, dst_rc, src_cr, dst_cr, partial, E);
    reduce_norms2<<<512, 256, 0, stream>>>(partial, cnt, norms);
    scanA<<<200, 256, 0, stream>>>(cnt, bsum);
    scanB<<<1, 256, 0, stream>>>(bsum, cbase);
    scanC<<<200, 512, 0, stream>>>(cnt, cbase, ptr_rc, ptr_cr, E);
    block_starts<<<400, 256, 0, stream>>>(partial, bstart, ptr_rc, ptr_cr);

    // ---- fused: CSR fill (latency-bound) + fp8/weight prep (streaming) ----
    csr_fill_prep<<<8 * HBLK + PBLK, 1024, 0, stream>>>(
        src_rc, dst_rc, w_rc, r_out_rc, pair_rc,
        src_cr, dst_cr, w_cr, r_out_cr, pair_cr, bstart, E,
        (const float4*)feat_row, (const float4*)feat_col,
        (unsigned*)f8_row, (unsigned*)f8_col, NROW * 64 / 4,
        W0_rc, W0_cr, W1_rc, W1_cr, wt);

    // ---- layer 1 ----
    gather64_2<<<2 * GGRID, 256, 0, stream>>>(f8_row, ptr_rc, pair_rc, agg_col,
                                              f8_col, ptr_cr, pair_cr, agg_row, NCOL);
    dense64_2<<<2 * DGRID, 256, 0, stream>>>(agg_col, r_in_rc, wt0_rc, b0_rc, h_col1,
                                             agg_row, r_in_cr, wt0_cr, b0_cr, h_row1, NCOL);

    // ---- layer 2: pre-transform h1@W1 -> fp8, then fused gather+relu+mean ----
    h1t_gemm2<<<2 * DGRID, 256, 0, stream>>>(h_row1, wt1_rc, ht_row,
                                             h_col1, wt1_cr, ht_col, NROW);
    gather_final<<<2 * GGRID, 256, 0, stream>>>(
        ht_row, ptr_rc, pair_rc, r_in_rc, b1_rc,
        ht_col, ptr_cr, pair_cr, r_in_cr, b1_cr,
        partsum, NCOL, 1.0f / NCOL);
    reduce_out<<<32, 128, 0, stream>>>(partsum, out, 2 * GGRID);
}